// Round 12
// baseline (506.384 us; speedup 1.0000x reference)
//
#include <hip/hip_runtime.h>
#include <hip/hip_bf16.h>

typedef __attribute__((ext_vector_type(8))) short short8;
typedef __attribute__((ext_vector_type(4))) short short4v;
typedef __attribute__((ext_vector_type(4))) float f32x4;
typedef __hip_bfloat16 bf;

__device__ __forceinline__ void gl_lds16(const void* g, void* l) {
  __builtin_amdgcn_global_load_lds(
      (const __attribute__((address_space(1))) unsigned int*)g,
      (__attribute__((address_space(3))) unsigned int*)l, 16, 0, 0);
}
__device__ __forceinline__ unsigned short f2b(float f) {
  bf h = __float2bfloat16(f);
  return *reinterpret_cast<unsigned short*>(&h);
}
__device__ __forceinline__ float b2f(unsigned short u) {
  unsigned v = ((unsigned)u) << 16;
  return __uint_as_float(v);
}

// ---------------- fused concat + LN1 -> bf16 (also writes A f32) ----------------
__global__ __launch_bounds__(256) void concat_ln_k(const float* __restrict__ x,
    const float* __restrict__ cls, const float* __restrict__ g,
    const float* __restrict__ b, float* __restrict__ A, bf* __restrict__ O)
{
  __shared__ float red[256];
  const long row = blockIdx.x; const int tid = threadIdx.x;
  const float* src = (row == 0) ? cls : (x + (row - 1) * 512);
  float v0 = src[tid], v1 = src[tid + 256];
  A[row * 512 + tid] = v0; A[row * 512 + tid + 256] = v1;
  red[tid] = v0 + v1; __syncthreads();
  for (int s = 128; s > 0; s >>= 1) { if (tid < s) red[tid] += red[tid + s]; __syncthreads(); }
  float mean = red[0] * (1.f / 512.f); __syncthreads();
  float d0 = v0 - mean, d1 = v1 - mean;
  red[tid] = d0 * d0 + d1 * d1; __syncthreads();
  for (int s = 128; s > 0; s >>= 1) { if (tid < s) red[tid] += red[tid + s]; __syncthreads(); }
  float rs = rsqrtf(red[0] * (1.f / 512.f) + 1e-5f);
  O[row * 512 + tid]       = __float2bfloat16(d0 * rs * g[tid] + b[tid]);
  O[row * 512 + tid + 256] = __float2bfloat16(d1 * rs * g[tid + 256] + b[tid + 256]);
}

// ---------------- fused LN -> bf16 ----------------
__global__ __launch_bounds__(256) void ln_bf16_k(const float* __restrict__ X,
    const float* __restrict__ g, const float* __restrict__ b,
    bf* __restrict__ O)
{
  __shared__ float red[256];
  const long row = blockIdx.x; const int tid = threadIdx.x;
  const float* r = X + row * 512;
  float v0 = r[tid], v1 = r[tid + 256];
  red[tid] = v0 + v1; __syncthreads();
  for (int s = 128; s > 0; s >>= 1) { if (tid < s) red[tid] += red[tid + s]; __syncthreads(); }
  float mean = red[0] * (1.f / 512.f); __syncthreads();
  float d0 = v0 - mean, d1 = v1 - mean;
  red[tid] = d0 * d0 + d1 * d1; __syncthreads();
  for (int s = 128; s > 0; s >>= 1) { if (tid < s) red[tid] += red[tid + s]; __syncthreads(); }
  float rs = rsqrtf(red[0] * (1.f / 512.f) + 1e-5f);
  O[row * 512 + tid]       = __float2bfloat16(d0 * rs * g[tid] + b[tid]);
  O[row * 512 + tid + 256] = __float2bfloat16(d1 * rs * g[tid + 256] + b[tid + 256]);
}

// ---------------- weight transpose f32[K][N] -> bf16[N][K] ----------------
__global__ __launch_bounds__(256) void tconv_k(const float* __restrict__ W,
    bf* __restrict__ WT, int K, int N)
{
  __shared__ float t[64][65];
  const int n0 = blockIdx.x << 6, k0 = blockIdx.y << 6;
  const int c = threadIdx.x & 63; const int r4 = threadIdx.x >> 6;
  #pragma unroll 4
  for (int i = 0; i < 16; i++) {
    int r = r4 * 16 + i;
    t[r][c] = W[(long)(k0 + r) * N + n0 + c];
  }
  __syncthreads();
  #pragma unroll 4
  for (int i = 0; i < 16; i++) {
    int r = r4 * 16 + i;
    WT[(long)(n0 + r) * K + k0 + c] = __float2bfloat16(t[c][r]);
  }
}

// ---------------- 256x256 dbuf bf16 MFMA GEMM, XCD-swizzled: C = A @ B^T ----------------
// 512 threads (8 waves, 2x4), BK=64, 128 KiB dynamic LDS double buffer.
// EPI: 1 = f32 + bias + residual; 2 = bf16 + bias + gelu; 3 = head-major Q/K/V bf16
template<int EPI>
__global__ __launch_bounds__(512) void gemm256(
    const bf* __restrict__ Ag, const bf* __restrict__ Bg,
    void* __restrict__ Cg, const float* __restrict__ Res,
    const float* __restrict__ bias, int K, int N,
    bf* __restrict__ Qb, bf* __restrict__ Kb, bf* __restrict__ Vb)
{
  extern __shared__ short LDS[];   // [2 buf][A|B][2 half][256][32]
  const int tid = threadIdx.x, lane = tid & 63, wid = tid >> 6;
  const int nwg = gridDim.x * gridDim.y;
  const int lin = blockIdx.y * gridDim.x + blockIdx.x;
  const int nl = (lin & 7) * (nwg >> 3) + (lin >> 3);
  const int bxi = nl % gridDim.x, byi = nl / gridDim.x;
  const int brow = byi << 8, bcol = bxi << 8;
  const int wr2 = (wid >> 2) << 7, wc2 = (wid & 3) << 6;
  const int fr = lane & 15, fs = lane >> 4;
  const int srow = lane >> 2, skp = (lane & 3) << 3;
  f32x4 acc[8][4];
  #pragma unroll
  for (int m = 0; m < 8; m++)
    #pragma unroll
    for (int n = 0; n < 4; n++) acc[m][n] = (f32x4){0.f, 0.f, 0.f, 0.f};

  const bf* Arow = Ag + (long)brow * K;
  const bf* Brow = Bg + (long)bcol * K;

  auto stage = [&](int bufi, int koff) {
    short* base = LDS + bufi * 32768;
    #pragma unroll
    for (int i = 0; i < 8; i++) {
      int c = (wid << 3) + i;                 // 0..63
      int mat = c >> 5, c5 = c & 31, rg = c5 >> 1, hf = c5 & 1;
      const bf* src = (mat ? Brow : Arow)
          + (long)(rg * 16 + srow) * K + koff + hf * 32 + skp;
      gl_lds16(src, base + mat * 16384 + hf * 8192 + rg * 512);
    }
  };

  stage(0, 0);
  __syncthreads();
  const int nk = K >> 6;
  for (int t = 0; t < nk; ++t) {
    const int buf = t & 1;
    if (t + 1 < nk) stage(buf ^ 1, (t + 1) << 6);
    const short* Ab = LDS + buf * 32768;
    const short* Bb = Ab + 16384;
    #pragma unroll
    for (int kk = 0; kk < 2; kk++) {
      short8 a[8];
      #pragma unroll
      for (int m = 0; m < 8; m++)
        a[m] = *(const short8*)&Ab[kk * 8192 + (wr2 + m * 16 + fr) * 32 + fs * 8];
      #pragma unroll
      for (int n = 0; n < 4; n++) {
        short8 b = *(const short8*)&Bb[kk * 8192 + (wc2 + n * 16 + fr) * 32 + fs * 8];
        #pragma unroll
        for (int m = 0; m < 8; m++)
          acc[m][n] = __builtin_amdgcn_mfma_f32_16x16x32_bf16(a[m], b, acc[m][n], 0, 0, 0);
      }
    }
    __syncthreads();
  }

  #pragma unroll
  for (int m = 0; m < 8; m++) {
    #pragma unroll
    for (int n = 0; n < 4; n++) {
      const int col = bcol + wc2 + n * 16 + fr;
      #pragma unroll
      for (int j = 0; j < 4; j++) {
        const long row = brow + wr2 + m * 16 + fs * 4 + j;
        float v = acc[m][n][j];
        if (EPI == 1) {
          v += bias[col] + Res[row * N + col];
          ((float*)Cg)[row * N + col] = v;
        } else if (EPI == 2) {
          v += bias[col];
          v = 0.5f * v * (1.f + erff(v * 0.70710678118654752f));
          ((bf*)Cg)[row * N + col] = __float2bfloat16(v);
        } else {
          int sect = col >> 9, h = (col >> 6) & 7, d = col & 63;
          long o = ((long)h * 8192 + row) * 64 + d;
          if (sect == 0)      Qb[o] = __float2bfloat16(v * 0.125f);
          else if (sect == 1) Kb[o] = __float2bfloat16(v);
          else                Vb[o] = __float2bfloat16(v);
        }
      }
    }
  }
}

// ---------------- pinv phase GEMM: 64x64 tiles, grid (4,4,8), XCD-swizzled per head ----------------
template<int CS, int DIAG>
__global__ __launch_bounds__(256) void pgemm_k(
    const bf* __restrict__ Ag, const bf* __restrict__ Bg,
    bf* __restrict__ Cg, bf* __restrict__ Tg, float alpha, float s)
{
  __shared__ __align__(16) short As[8][64][32];
  __shared__ __align__(16) short Bs[8][64][32];
  short (*Tt)[68] = (short(*)[68])&As[0][0][0];
  const int tid = threadIdx.x, lane = tid & 63, wid = tid >> 6;
  const int lin = (blockIdx.z * 4 + blockIdx.y) * 4 + blockIdx.x;
  const int nl = (lin & 7) * 16 + (lin >> 3);
  const int bz = nl >> 4, rem = nl & 15;
  const long base = (long)bz << 16;
  const int brow = (rem >> 2) << 6, bcol = (rem & 3) << 6;
  const int wr = (wid >> 1) << 5, wc = (wid & 1) << 5;
  const int fr = lane & 15, fs = lane >> 4;
  const int srow = lane >> 2, skp = (lane & 3) << 3;
  const bf* Arow = Ag + base + (long)brow * 256;
  const bf* Brow = Bg + base + (long)bcol * 256;
  #pragma unroll
  for (int i = 0; i < 16; i++) {
    int c = (wid << 4) + i;
    int mat = c >> 5, c5 = c & 31, rg = c5 >> 3, ks = c5 & 7;
    const bf* src = (mat ? Brow : Arow) + (long)(rg * 16 + srow) * 256 + ks * 32 + skp;
    gl_lds16(src, mat ? &Bs[ks][rg * 16][0] : &As[ks][rg * 16][0]);
  }
  __syncthreads();
  f32x4 acc[2][2];
  #pragma unroll
  for (int m = 0; m < 2; m++)
    #pragma unroll
    for (int n = 0; n < 2; n++) acc[m][n] = (f32x4){0.f, 0.f, 0.f, 0.f};
  #pragma unroll
  for (int ks = 0; ks < 8; ks++) {
    short8 a[2], b[2];
    #pragma unroll
    for (int m = 0; m < 2; m++)
      a[m] = *(const short8*)&As[ks][wr + m * 16 + fr][fs * 8];
    #pragma unroll
    for (int n = 0; n < 2; n++)
      b[n] = *(const short8*)&Bs[ks][wc + n * 16 + fr][fs * 8];
    #pragma unroll
    for (int m = 0; m < 2; m++)
      #pragma unroll
      for (int n = 0; n < 2; n++)
        acc[m][n] = __builtin_amdgcn_mfma_f32_16x16x32_bf16(a[m], b[n], acc[m][n], 0, 0, 0);
  }
  if (CS) {
    #pragma unroll
    for (int m = 0; m < 2; m++)
      #pragma unroll
      for (int n = 0; n < 2; n++) {
        const int col = bcol + wc + n * 16 + fr;
        #pragma unroll
        for (int j = 0; j < 4; j++)
          (Cg + base)[(long)(brow + wr + m * 16 + fs * 4 + j) * 256 + col] =
              __float2bfloat16(acc[m][n][j] * alpha);
      }
  }
  __syncthreads();
  #pragma unroll
  for (int m = 0; m < 2; m++)
    #pragma unroll
    for (int n = 0; n < 2; n++) {
      const int lcol = wc + n * 16 + fr;
      #pragma unroll
      for (int j = 0; j < 4; j++) {
        const int lrow = wr + m * 16 + fs * 4 + j;
        float v = acc[m][n][j] * alpha;
        float o = DIAG ? (((brow + lrow) == (bcol + lcol)) ? (s - v) : (-v)) : v;
        Tt[lcol][lrow] = (short)f2b(o);
      }
    }
  __syncthreads();
  {
    const int lcol = tid >> 2, q = tid & 3;
    short8 w0 = *(const short8*)&Tt[lcol][q * 16];
    short8 w1 = *(const short8*)&Tt[lcol][q * 16 + 8];
    bf* dst = Tg + base + (long)(bcol + lcol) * 256 + brow + q * 16;
    *(short8*)dst = w0;
    *(short8*)(dst + 8) = w1;
  }
}

// ---------------- batched bf16 MFMA GEMM (CM only), K=256, dbuf ----------------
template<int EPI>
__global__ __launch_bounds__(256) void bgemm(
    const bf* __restrict__ Ag, const bf* __restrict__ Bg,
    void* __restrict__ Cg, bf* __restrict__ Tg,
    int Nc, float alpha, float s,
    long lda, long ldb, long ldc, long ldt,
    long sA, long sB, long sC, long sT)
{
  __shared__ __align__(16) short As[2][2][128][32];
  __shared__ __align__(16) short Bs[2][2][128][32];
  const int tid = threadIdx.x, lane = tid & 63, wid = tid >> 6;
  const int hh = blockIdx.z;
  const int brow = blockIdx.y << 7, bcol = blockIdx.x << 7;
  const int wr = (wid >> 1) << 6, wc = (wid & 1) << 6;
  const int fr = lane & 15, fs = lane >> 4;
  const int srow = lane >> 2, skp = (lane & 3) << 3;
  f32x4 acc[4][4];
  #pragma unroll
  for (int m = 0; m < 4; m++)
    #pragma unroll
    for (int n = 0; n < 4; n++) acc[m][n] = (f32x4){0.f, 0.f, 0.f, 0.f};

  const bf* Arow = Ag + hh * sA + (long)brow * lda;
  const bf* Brow = Bg + hh * sB + (long)bcol * ldb;

  auto stage = [&](int bufi, int koff) {
    #pragma unroll
    for (int i = 0; i < 4; i++) {
      int c = (wid << 2) + i, rg = c >> 1, hf = c & 1;
      gl_lds16(Arow + (long)(rg * 16 + srow) * lda + koff + hf * 32 + skp,
               &As[bufi][hf][rg * 16][0]);
      gl_lds16(Brow + (long)(rg * 16 + srow) * ldb + koff + hf * 32 + skp,
               &Bs[bufi][hf][rg * 16][0]);
    }
  };

  stage(0, 0);
  __syncthreads();
  #pragma unroll
  for (int t = 0; t < 4; ++t) {
    const int buf = t & 1;
    if (t < 3) stage(buf ^ 1, (t + 1) << 6);
    #pragma unroll
    for (int kk = 0; kk < 2; kk++) {
      short8 a[4], b[4];
      #pragma unroll
      for (int m = 0; m < 4; m++)
        a[m] = *(const short8*)&As[buf][kk][wr + m * 16 + fr][fs * 8];
      #pragma unroll
      for (int n = 0; n < 4; n++)
        b[n] = *(const short8*)&Bs[buf][kk][wc + n * 16 + fr][fs * 8];
      #pragma unroll
      for (int m = 0; m < 4; m++)
        #pragma unroll
        for (int n = 0; n < 4; n++)
          acc[m][n] = __builtin_amdgcn_mfma_f32_16x16x32_bf16(a[m], b[n], acc[m][n], 0, 0, 0);
    }
    __syncthreads();
  }

  #pragma unroll
  for (int m = 0; m < 4; m++) {
    #pragma unroll
    for (int n = 0; n < 4; n++) {
      const int col = bcol + wc + n * 16 + fr;
      const int rbase = brow + wr + m * 16 + fs * 4;
      if (EPI != 6 || col < Nc) {
        bf* Tb = Tg + hh * sT;
        short4v tv;
        #pragma unroll
        for (int j = 0; j < 4; j++) tv[j] = (short)f2b(acc[m][n][j] * alpha);
        *(short4v*)&Tb[(long)col * ldt + rbase] = tv;
      }
    }
  }
}

// ---------------- fp32 tiled GEMM (attn2 logits only) ----------------
__global__ __launch_bounds__(256) void sgemm_k(
    const float* __restrict__ A, const float* __restrict__ Bw,
    float* __restrict__ C,
    int K, long lda, long ldb, long ldc,
    long sA, long sB, long sC)
{
  __shared__ float As[16][68];
  __shared__ __align__(16) float Bs[16][68];
  const int tid = threadIdx.x;
  const int zz = blockIdx.z;
  const float* Ab = A + zz * sA;
  const float* Bb = Bw + zz * sB;
  float* Cb = C + zz * sC;
  const int brow = blockIdx.y * 64;
  const int bcol = blockIdx.x * 64;
  const int tm = tid >> 4, tn = tid & 15;
  const int lam = tid >> 2;
  const int lak = (tid & 3) << 2;
  const int lbk = tid >> 4;
  const int lbn = (tid & 15) << 2;
  float acc[4][4];
  #pragma unroll
  for (int i = 0; i < 4; i++)
    #pragma unroll
    for (int j = 0; j < 4; j++) acc[i][j] = 0.f;

  for (int k0 = 0; k0 < K; k0 += 16) {
    float4 av = *(const float4*)&Ab[(long)(brow + lam) * lda + k0 + lak];
    As[lak + 0][lam] = av.x; As[lak + 1][lam] = av.y;
    As[lak + 2][lam] = av.z; As[lak + 3][lam] = av.w;
    float4 bv = *(const float4*)&Bb[(long)(k0 + lbk) * ldb + bcol + lbn];
    *(float4*)&Bs[lbk][lbn] = bv;
    __syncthreads();
    #pragma unroll
    for (int kk = 0; kk < 16; kk++) {
      float a0 = As[kk][(tm << 2) + 0], a1 = As[kk][(tm << 2) + 1];
      float a2 = As[kk][(tm << 2) + 2], a3 = As[kk][(tm << 2) + 3];
      float b0 = Bs[kk][(tn << 2) + 0], b1 = Bs[kk][(tn << 2) + 1];
      float b2 = Bs[kk][(tn << 2) + 2], b3 = Bs[kk][(tn << 2) + 3];
      acc[0][0] += a0 * b0; acc[0][1] += a0 * b1; acc[0][2] += a0 * b2; acc[0][3] += a0 * b3;
      acc[1][0] += a1 * b0; acc[1][1] += a1 * b1; acc[1][2] += a1 * b2; acc[1][3] += a1 * b3;
      acc[2][0] += a2 * b0; acc[2][1] += a2 * b1; acc[2][2] += a2 * b2; acc[2][3] += a2 * b3;
      acc[3][0] += a3 * b0; acc[3][1] += a3 * b1; acc[3][2] += a3 * b2; acc[3][3] += a3 * b3;
    }
    __syncthreads();
  }
  #pragma unroll
  for (int i = 0; i < 4; i++) {
    const long row = brow + (tm << 2) + i;
    #pragma unroll
    for (int j = 0; j < 4; j++) {
      const int col = bcol + (tn << 2) + j;
      Cb[row * ldc + col] = acc[i][j];
    }
  }
}

// ---------------- landmarks from bf16 Q/K ----------------
__global__ __launch_bounds__(256) void landmarks_k(const bf* __restrict__ Qb,
    const bf* __restrict__ Kb,
    float* __restrict__ QL, float* __restrict__ KLT,
    bf* __restrict__ QLb, bf* __restrict__ KLb)
{
  int t = blockIdx.x * 256 + threadIdx.x;
  int d = t & 63; int m = (t >> 6) & 255; int h = t >> 14;
  const unsigned short* qp = (const unsigned short*)Qb + ((long)h * 8192 + m * 32) * 64 + d;
  const unsigned short* kp = (const unsigned short*)Kb + ((long)h * 8192 + m * 32) * 64 + d;
  float sq = 0.f, sk = 0.f;
  for (int i = 0; i < 32; i++) { sq += b2f(qp[i * 64]); sk += b2f(kp[i * 64]); }
  float qv = sq * (1.f / 32.f);
  QL[t] = qv;
  QLb[t] = __float2bfloat16(qv);
  float kv = sk * (1.f / 32.f);
  KLb[t] = __float2bfloat16(kv);
  KLT[(h << 14) + (d << 8) + m] = kv;
}

// ---------------- V transpose (bf16 -> bf16): VT[h][d][n] ----------------
__global__ __launch_bounds__(256) void vt_k(const bf* __restrict__ Vb,
    bf* __restrict__ VT)
{
  __shared__ unsigned short t[64][68];
  const int h = blockIdx.x & 7; const int n0 = (blockIdx.x >> 3) << 6;
  const int c = threadIdx.x & 63; const int r4 = threadIdx.x >> 6;
  const unsigned short* vp = (const unsigned short*)Vb;
  unsigned short* vo = (unsigned short*)VT;
  #pragma unroll 4
  for (int i = 0; i < 16; i++) {
    int r = r4 * 16 + i;
    t[r][c] = vp[((long)h * 8192 + n0 + r) * 64 + c];
  }
  __syncthreads();
  #pragma unroll 4
  for (int i = 0; i < 16; i++) {
    int d = r4 * 16 + i;
    vo[((long)(h << 6) + d) * 8192 + n0 + c] = t[c][d];
  }
}

// ---------------- row softmax, width 256, f32 in place ----------------
__global__ __launch_bounds__(256) void softmax256_k(float* __restrict__ X)
{
  __shared__ float red[256];
  const long row = blockIdx.x; const int tid = threadIdx.x;
  float v = X[row * 256 + tid];
  red[tid] = v; __syncthreads();
  for (int s = 128; s > 0; s >>= 1) { if (tid < s) red[tid] = fmaxf(red[tid], red[tid + s]); __syncthreads(); }
  float M = red[0]; __syncthreads();
  float e = __expf(v - M);
  red[tid] = e; __syncthreads();
  for (int s = 128; s > 0; s >>= 1) { if (tid < s) red[tid] += red[tid + s]; __syncthreads(); }
  float S = red[0];
  X[row * 256 + tid] = e / S;
}

// ---------------- pinv scalars ----------------
__global__ __launch_bounds__(256) void colsum_k(const float* __restrict__ X, float* __restrict__ out)
{
  int t = blockIdx.x * 256 + threadIdx.x; int h = t >> 8; int j = t & 255;
  const float* c = X + ((long)h << 16) + j;
  float s = 0.f;
  for (int i = 0; i < 256; i++) s += fabsf(c[(long)i << 8]);
  out[t] = s;
}
__global__ __launch_bounds__(256) void invscale_k(const float* __restrict__ cols,
    float* __restrict__ inv)
{
  __shared__ float red[256];
  int tid = threadIdx.x;
  float mc = -1e30f;
  for (int i = tid; i < 2048; i += 256) mc = fmaxf(mc, cols[i]);
  red[tid] = mc; __syncthreads();
  for (int s = 128; s > 0; s >>= 1) { if (tid < s) red[tid] = fmaxf(red[tid], red[tid + s]); __syncthreads(); }
  if (tid == 0) inv[0] = 1.0f / red[0];
}

// ---------------- pinv init: Xbf, z0 = X^T*inv, z0T = X*inv ----------------
__global__ __launch_bounds__(256) void xz_init_k(const float* __restrict__ ATT2,
    const float* __restrict__ inv, bf* __restrict__ Xb,
    bf* __restrict__ z0, bf* __restrict__ z0T)
{
  __shared__ float t[64][65];
  const int h = blockIdx.z;
  const int j0 = blockIdx.x << 6, i0 = blockIdx.y << 6;
  const int c = threadIdx.x & 63; const int r4 = threadIdx.x >> 6;
  const float iv = inv[0];
  #pragma unroll 4
  for (int i = 0; i < 16; i++) {
    int r = r4 * 16 + i;
    float v = ATT2[((long)h << 16) + (long)(i0 + r) * 256 + j0 + c];
    t[r][c] = v;
    Xb[((long)h << 16) + (long)(i0 + r) * 256 + j0 + c]  = __float2bfloat16(v);
    z0T[((long)h << 16) + (long)(i0 + r) * 256 + j0 + c] = __float2bfloat16(v * iv);
  }
  __syncthreads();
  #pragma unroll 4
  for (int i = 0; i < 16; i++) {
    int r = r4 * 16 + i;
    z0[((long)h << 16) + (long)(j0 + r) * 256 + i0 + c] = __float2bfloat16(t[c][r] * iv);
  }
}

// ---------------- flash attn3, XCD-swizzled per head ----------------
__global__ __launch_bounds__(256) void attn3f_k(
    const bf* __restrict__ Qlb, const bf* __restrict__ Kb, const bf* __restrict__ Vt,
    float* __restrict__ Op, float* __restrict__ Mp, float* __restrict__ Lp)
{
  __shared__ __align__(16) short Qs[2][128][32];
  __shared__ __align__(16) short Ks[2][128][32];
  __shared__ __align__(16) short Vs[4][64][32];
  __shared__ __align__(16) short Ps[4][4][32][32];
  const int tid = threadIdx.x, lane = tid & 63, wid = tid >> 6;
  const int fr = lane & 15, fs = lane >> 4;
  const int srow = lane >> 2, skp = (lane & 3) << 3;
  const int lin = (blockIdx.z * 2 + blockIdx.y) * 16 + blockIdx.x;
  const int nl = (lin & 7) * 32 + (lin >> 3);
  const int chunk = nl & 15, mt = (nl >> 4) & 1, h = nl >> 5;
  const int wrb = wid << 5;
  const bf* Qg = Qlb + ((long)h * 256 + mt * 128) * 64;
  #pragma unroll
  for (int i = 0; i < 4; i++) {
    int c = (wid << 2) + i, rg = c >> 1, hf = c & 1;
    gl_lds16(Qg + (long)(rg * 16 + srow) * 64 + hf * 32 + skp, &Qs[hf][rg * 16][0]);
  }
  f32x4 acc2[2][4];
  float mrun[2][4], lrun[2][4];
  #pragma unroll
  for (int m = 0; m < 2; m++)
    #pragma unroll
    for (int n = 0; n < 4; n++) { acc2[m][n] = (f32x4){0.f,0.f,0.f,0.f}; mrun[m][n] = -1e30f; lrun[m][n] = 0.f; }

  for (int t = 0; t < 4; t++) {
    const int key0 = (chunk << 9) + (t << 7);
    const bf* Kg = Kb + ((long)h * 8192 + key0) * 64;
    #pragma unroll
    for (int i = 0; i < 4; i++) {
      int c = (wid << 2) + i, rg = c >> 1, hf = c & 1;
      gl_lds16(Kg + (long)(rg * 16 + srow) * 64 + hf * 32 + skp, &Ks[hf][rg * 16][0]);
    }
    #pragma unroll
    for (int i = 0; i < 4; i++) {
      int c = (wid << 2) + i, dg = c >> 2, ks = c & 3;
      gl_lds16(Vt + ((long)h * 64 + dg * 16 + srow) * 8192 + key0 + ks * 32 + skp,
               &Vs[ks][dg * 16][0]);
    }
    __syncthreads();
    f32x4 lac[2][8];
    #pragma unroll
    for (int m = 0; m < 2; m++)
      #pragma unroll
      for (int n = 0; n < 8; n++) lac[m][n] = (f32x4){0.f,0.f,0.f,0.f};
    #pragma unroll
    for (int kk = 0; kk < 2; kk++) {
      short8 a[2];
      #pragma unroll
      for (int m = 0; m < 2; m++)
        a[m] = *(const short8*)&Qs[kk][wrb + m * 16 + fr][fs * 8];
      #pragma unroll
      for (int n = 0; n < 8; n++) {
        short8 b = *(const short8*)&Ks[kk][n * 16 + fr][fs * 8];
        #pragma unroll
        for (int m = 0; m < 2; m++)
          lac[m][n] = __builtin_amdgcn_mfma_f32_16x16x32_bf16(a[m], b, lac[m][n], 0, 0, 0);
      }
    }
    #pragma unroll
    for (int m = 0; m < 2; m++) {
      #pragma unroll
      for (int j = 0; j < 4; j++) {
        float tmax = lac[m][0][j];
        #pragma unroll
        for (int n = 1; n < 8; n++) tmax = fmaxf(tmax, lac[m][n][j]);
        tmax = fmaxf(tmax, __shfl_xor(tmax, 1));
        tmax = fmaxf(tmax, __shfl_xor(tmax, 2));
        tmax = fmaxf(tmax, __shfl_xor(tmax, 4));
        tmax = fmaxf(tmax, __shfl_xor(tmax, 8));
        float mnew = fmaxf(mrun[m][j], tmax);
        float sc = __expf(mrun[m][j] - mnew);
        #pragma unroll
        for (int n2 = 0; n2 < 4; n2++) acc2[m][n2][j] *= sc;
        float lsum = 0.f;
        #pragma unroll
        for (int n = 0; n < 8; n++) {
          float p = __expf(lac[m][n][j] - mnew);
          lac[m][n][j] = p; lsum += p;
        }
        lsum += __shfl_xor(lsum, 1);
        lsum += __shfl_xor(lsum, 2);
        lsum += __shfl_xor(lsum, 4);
        lsum += __shfl_xor(lsum, 8);
        lrun[m][j] = lrun[m][j] * sc + lsum;
        mrun[m][j] = mnew;
      }
    }
    #pragma unroll
    for (int m = 0; m < 2; m++)
      #pragma unroll
      for (int n = 0; n < 8; n++) {
        int col = n * 16 + fr;
        #pragma unroll
        for (int j = 0; j < 4; j++)
          Ps[wid][col >> 5][m * 16 + fs * 4 + j][col & 31] = (short)f2b(lac[m][n][j]);
      }
    #pragma unroll
    for (int ks = 0; ks < 4; ks++) {
      short8 a2[2];
      #pragma unroll
      for (int m = 0; m < 2; m++)
        a2[m] = *(const short8*)&Ps[wid][ks][m * 16 + fr][fs * 8];
      #pragma unroll
      for (int n = 0; n < 4; n++) {
        short8 b2 = *(const short8*)&Vs[ks][n * 16 + fr][fs * 8];
        #pragma unroll
        for (int m = 0; m < 2; m++)
          acc2[m][n] = __builtin_amdgcn_mfma_f32_16x16x32_bf16(a2[m], b2, acc2[m][n], 0, 0, 0);
      }
    }
    __syncthreads();
  }
  const long base = (long)(chunk * 8 + h) * 2 + mt;
  #pragma unroll
  for (int m = 0; m < 2; m++)
    #pragma unroll
    for (int n = 0; n < 4; n++) {
      int col = n * 16 + fr;
      #pragma unroll
      for (int j = 0; j < 4; j++)
        Op[base * 8192 + (long)(wrb + m * 16 + fs * 4 + j) * 64 + col] = acc2[m][n][j];
    }
  if (fr == 0) {
    #pragma unroll
    for (int m = 0; m < 2; m++)
      #pragma unroll
      for (int j = 0; j < 4; j++) {
        int r = wrb + m * 16 + fs * 4 + j;
        Mp[base * 128 + r] = mrun[m][j];
        Lp[base * 128 + r] = lrun[m][j];
      }
  }
}

// ---------------- flash attn3 combine (parallel, 128 blocks) -> AVT bf16 [h][d][m] ----------------
__global__ __launch_bounds__(256) void attn3c_k(
    const float* __restrict__ Op, const float* __restrict__ Mp,
    const float* __restrict__ Lp, bf* __restrict__ AVT)
{
  __shared__ float wm[16][16];
  __shared__ float wl[16][16];
  const int bid = blockIdx.x;
  const int h = bid >> 4, mt = (bid >> 3) & 1, rs = bid & 7;
  const int tid = threadIdx.x;
  const int r0 = rs * 16;
  {
    int c = tid >> 4, r = tid & 15;
    long idx = ((long)(c * 8 + h) * 2 + mt) * 128 + r0 + r;
    wm[c][r] = Mp[idx];
    wl[c][r] = Lp[idx];
  }
  __syncthreads();
  if (tid < 16) {
    int r = tid;
    float M = wm[0][r];
    #pragma unroll
    for (int c = 1; c < 16; c++) M = fmaxf(M, wm[c][r]);
    float D = 0.f;
    #pragma unroll
    for (int c = 0; c < 16; c++) D += __expf(wm[c][r] - M) * wl[c][r];
    float rv = 1.0f / D;
    #pragma unroll
    for (int c = 0; c < 16; c++) wm[c][r] = __expf(wm[c][r] - M) * rv;
  }
  __syncthreads();
  #pragma unroll
  for (int i = 0; i < 4; i++) {
    int idx = i * 256 + tid;
    int r = idx >> 6, d = idx & 63;
    float s = 0.f;
    #pragma unroll
    for (int c = 0; c < 16; c++)
      s += wm[c][r] * Op[((long)(c * 8 + h) * 2 + mt) * 8192 + (long)(r0 + r) * 64 + d];
    AVT[(long)h * 16384 + d * 256 + mt * 128 + r0 + r] = __float2bfloat16(s);
  }
}

// ---------------- fused attn1: logits -> softmax -> @CM -> Bhbf ----------------
__global__ __launch_bounds__(256) void attn1_k(
    const bf* __restrict__ Qb, const bf* __restrict__ KLb,
    const bf* __restrict__ CMT, bf* __restrict__ Bhb)
{
  __shared__ __align__(16) char U[65536];
  short (*As)[128][32] = (short(*)[128][32])U;
  short (*Bs)[256][32] = (short(*)[256][32])(U + 16384);
  short (*Ps)[128][32] = (short(*)[128][32])U;
  __shared__ __align__(16) short Cs[8][64][32];
  __shared__ float red[2][2][128];

  const int tid = threadIdx.x;
  const int lane = tid & 63, wid = tid >> 6;
  const int fr = lane & 15, fs = lane >> 4;
  const int srow = lane >> 2, skp = (lane & 3) << 3;
  const int n0 = blockIdx.x << 7, h = blockIdx.y;
  const int half = wid & 1, wrb = (wid >> 1) << 6;

  const bf* Aq = Qb  + (long)h * 524288 + (long)n0 * 64;
  const bf* Bk = KLb + (long)h * 16384;
  const bf* Cm = CMT + (long)h * 16384;

  for (int i = 0; i < 20; i++) {
    int c = wid * 20 + i;
    if (c < 16) {
      int rg = c >> 1, hf = c & 1;
      gl_lds16(Aq + (long)(rg * 16 + srow) * 64 + hf * 32 + skp, &As[hf][rg * 16][0]);
    } else if (c < 48) {
      int c2 = c - 16; int rg = c2 >> 1, hf = c2 & 1;
      gl_lds16(Bk + (long)(rg * 16 + srow) * 64 + hf * 32 + skp, &Bs[hf][rg * 16][0]);
    } else {
      int c3 = c - 48; int rg = c3 >> 3, ks = c3 & 7;
      gl_lds16(Cm + (long)(rg * 16 + srow) * 256 + ks * 32 + skp, &Cs[ks][rg * 16][0]);
    }
  }
  __syncthreads();

  f32x4 acc[4][8];
  #pragma unroll
  for (int m = 0; m < 4; m++)
    #pragma unroll
    for (int n = 0; n < 8; n++) acc[m][n] = (f32x4){0.f, 0.f, 0.f, 0.f};
  #pragma unroll
  for (int kk = 0; kk < 2; kk++) {
    short8 a[4];
    #pragma unroll
    for (int m = 0; m < 4; m++)
      a[m] = *(const short8*)&As[kk][wrb + m * 16 + fr][fs * 8];
    #pragma unroll
    for (int n = 0; n < 8; n++) {
      short8 b = *(const short8*)&Bs[kk][half * 128 + n * 16 + fr][fs * 8];
      #pragma unroll
      for (int m = 0; m < 4; m++)
        acc[m][n] = __builtin_amdgcn_mfma_f32_16x16x32_bf16(a[m], b, acc[m][n], 0, 0, 0);
    }
  }

  #pragma unroll
  for (int m = 0; m < 4; m++)
    #pragma unroll
    for (int j = 0; j < 4; j++) {
      float mx = -1e30f;
      #pragma unroll
      for (int n = 0; n < 8; n++) mx = fmaxf(mx, acc[m][n][j]);
      mx = fmaxf(mx, __shfl_xor(mx, 1));
      mx = fmaxf(mx, __shfl_xor(mx, 2));
      mx = fmaxf(mx, __shfl_xor(mx, 4));
      mx = fmaxf(mx, __shfl_xor(mx, 8));
      int rloc = wrb + m * 16 + fs * 4 + j;
      if (fr == 0) red[0][half][rloc] = mx;
    }
  __syncthreads();
  #pragma unroll
  for (int m = 0; m < 4; m++)
    #pragma unroll
    for (int j = 0; j < 4; j++) {
      int rloc = wrb + m * 16 + fs * 4 + j;
      float Mx = fmaxf(red[0][0][rloc], red[0][1][rloc]);
      float s = 0.f;
      #pragma unroll
      for (int n = 0; n < 8; n++) {
        float e = __expf(acc[m][n][j] - Mx);
        acc[m][n][j] = e; s += e;
      }
      s += __shfl_xor(s, 1);
      s += __shfl_xor(s, 2);
      s += __shfl_xor(s, 4);
      s += __shfl_xor(s, 8);
      if (fr == 0) red[1][half][rloc] = s;
    }
  __syncthreads();
  #pragma unroll
  for (int m = 0; m < 4; m++)
    #pragma unroll
    for (int j = 0; j < 4; j++) {
      int rloc = wrb + m * 16 + fs * 4 + j;
      float inv = 1.0f / (red[1][0][rloc] + red[1][1][rloc]);
      #pragma unroll
      for (int n = 0; n < 8; n++) {
        int col = half * 128 + n * 16 + fr;
        Ps[col >> 5][rloc][col & 31] = (short)f2b(acc[m][n][j] * inv);
      }
    }
  __syncthreads();

  f32x4 acc2[4][2];
  #pragma unroll
  for (int m = 0; m < 4; m++)
    #pragma unroll
    for (int n = 0; n < 2; n++) acc2[m][n] = (f32x4){0.f, 0.f, 0.f, 0.f};
  const int wc2 = half * 32;
  #pragma unroll
  for (int kk = 0; kk < 8; kk++) {
    short8 a2[4];
    #pragma unroll
    for (int m = 0; m < 4; m++)
      a2[m] = *(const short8*)&Ps[kk][wrb + m * 16 + fr][fs * 8];
    #pragma unroll
    for (int n = 0; n < 2; n++) {
      short8 b2 = *(const short8*)&Cs[kk][wc2 + n * 16 + fr][fs * 8];
      #pragma unroll
      for (int m = 0; m < 4; m++)
        acc2[m][n] = __builtin_amdgcn_mfma_f32_16x16x32_bf16(a2[m], b2, acc2[m][n], 0, 0, 0);
    }
  }
  #pragma unroll
  for (int m = 0; m < 4; m++)
    #pragma unroll
    for (int n = 0; n < 2; n++) {
      int col = wc2 + n * 16 + fr;
      #pragma unroll
      for (int j = 0; j < 4; j++) {
        long row = n0 + wrb + m * 16 + fs * 4 + j;
        Bhb[row * 512 + h * 64 + col] = __float2bfloat16(acc2[m][n][j]);
      }
    }
}

// ---------------- depthwise conv residual, bf16 RMW into Bhbf ----------------
__global__ __launch_bounds__(256) void convres_k(const bf* __restrict__ Vb,
    const float* __restrict__ W, bf* __restrict__ Bhb)
{
  const int gid = blockIdx.x * 256 + threadIdx.x;
  const int n = gid >> 7, q = gid & 127;
  const int j0 = q << 2, h = j0 >> 6, d0 = j0 & 63;
  float a0 = 0.f, a1 = 0.f, a2 = 0.f, a3 = 0.f;
  const unsigned short* vb = (const unsigned short*)Vb + (long)h * 524288 + d0;
  #pragma unroll
  for (int kk = 0; kk < 33; kk++) {
    int nn = n + kk - 16;
    if (nn >= 0 && nn < 8192) {
      float w = W[h * 33 + kk];
      uint2 raw = *(const uint2*)(vb + (long)nn * 64);
      a0 += w * b2f(raw.x & 0xffff); a1 += w * b2f(raw.x >> 16);
      a2 += w * b2f(raw.y & 0xffff); a3 += w * b2f(raw.y >> 16);
    }
  }
  unsigned short* o = (unsigned short*)Bhb + (long)n * 512 + j0;
  uint2 cur = *(uint2*)o;
  uint2 outv;
  outv.x = (unsigned)f2b(b2f(cur.x & 0xffff) + a0) | ((unsigned)f2b(b2f(cur.x >> 16) + a1) << 16);
  outv.y = (unsigned)f2b(b2f(cur.y & 0xffff) + a2) | ((unsigned)f2b(b2f(cur.y >> 16) + a3) << 16);
  *(uint2*)o = outv;
}

// ---------------- host ----------------
extern "C" void kernel_launch(void* const* d_in, const int* in_sizes, int n_in,
                              void* d_out, int out_size, void* d_ws, size_t ws_size,
                              hipStream_t stream)
{
  const float* x     = (const float*)d_in[0];
  const float* cls   = (const float*)d_in[1];
  const float* ln1g  = (const float*)d_in[2];
  const float* ln1b  = (const float*)d_in[3];
  const float* wqkv  = (const float*)d_in[4];
  const float* wout  = (const float*)d_in[5];
  const float* bout  = (const float*)d_in[6];
  const float* convw = (const float*)d_in[7];
  const float* ln2g  = (const float*)d_in[8];
  const float* ln2b  = (const float*)d_in[9];
  const float* w1    = (const float*)d_in[10];
  const float* b1    = (const float*)d_in[11];
  const float* w2    = (const float*)d_in[12];
  const float* b2    = (const float*)d_in[13];
  float* out = (float*)d_out;
  float* ws  = (float*)d_ws;

  const int DLDS = 131072;
  hipFuncSetAttribute((const void*)gemm256<1>, hipFuncAttributeMaxDynamicSharedMemorySize, DLDS);
  hipFuncSetAttribute((const void*)gemm256<2>, hipFuncAttributeMaxDynamicSharedMemorySize, DLDS);
  hipFuncSetAttribute((const void*)gemm256<3>, hipFuncAttributeMaxDynamicSharedMemorySize, DLDS);

  float* A     = ws + 0;              // [8192][512] f32
  float* QL    = ws + 4194304;
  float* KLT   = ws + 4325376;
  float* ATT2  = ws + 4456448;
  float* csum  = ws + 4980736;
  float* inv   = ws + 4982784;        // 8
  float* Opart = ws + 4982800;        // [16][8][2][128][64] f32
  float* Mpart = ws + 7079952;        // [16][8][2][128]
  float* Lpart = ws + 7112720;
  bf* Qbf  = (bf*)(ws + 7145488);     // [8][8192][64] prescaled 0.125
  bf* Kbf  = (bf*)(ws + 9242640);
  bf* Vbf  = (bf*)(ws + 11339792);
  bf* VT   = (bf*)(ws + 13436944);    // [8][64][8192]
  bf* QLbf = (bf*)(ws + 15534096);
  bf* KLbf = (bf*)(ws + 15599632);
  bf* Xbf  = (bf*)(ws + 15665168);    // [8][256][256]
  bf* zA   = (bf*)(ws + 15927312);
  bf* zAT  = (bf*)(ws + 16189456);
  bf* zB   = (bf*)(ws + 16451600);
  bf* zBT  = (bf*)(ws + 16713744);
  bf* Gbf  = (bf*)(ws + 16975888);
  bf* TB0  = (bf*)(ws + 17238032);
  bf* TB1  = (bf*)(ws + 17500176);
  bf* AVT  = (bf*)(ws + 17762320);    // [8][64][256]
  bf* CMT  = (bf*)(ws + 17827856);
  float* R = ws + 17893392;           // reusable region
  bf* wqkvT = (bf*)R;                 // [1536][512]
  bf* ln1bf = (bf*)(R + 393216);      // [8192][512]
  bf* Bhbf  = (bf*)(R + 393216);      // aliases ln1bf after it dies
  bf* FF1bf = (bf*)R;                 // [8192][2048] after wqkvT/Bhbf dead
  bf* w1T   = Kbf;                    // aliases (Kbf dead after attn3f)
  bf* w2T   = Kbf + 1048576;
  bf* woutT = Kbf + 2097152;
  bf* ln2bf = VT;                     // aliases (VT dead after attn3f)

  concat_ln_k<<<8192, 256, 0, stream>>>(x, cls, ln1g, ln1b, A, ln1bf);
  tconv_k<<<dim3(24, 8), 256, 0, stream>>>(wqkv, wqkvT, 512, 1536);
  gemm256<3><<<dim3(6, 32), 512, DLDS, stream>>>(ln1bf, wqkvT, nullptr, nullptr, nullptr,
      512, 1536, Qbf, Kbf, Vbf);
  landmarks_k<<<512, 256, 0, stream>>>(Qbf, Kbf, QL, KLT, QLbf, KLbf);
  vt_k<<<1024, 256, 0, stream>>>(Vbf, VT);
  sgemm_k<<<dim3(4, 4, 8), 256, 0, stream>>>(QL, KLT, ATT2,
      64, 64, 256, 256, 16384, 16384, 65536);
  softmax256_k<<<2048, 256, 0, stream>>>(ATT2);
  colsum_k<<<8, 256, 0, stream>>>(ATT2, csum);
  invscale_k<<<1, 256, 0, stream>>>(csum, inv);
  xz_init_k<<<dim3(4, 4, 8), 256, 0, stream>>>(ATT2, inv, Xbf, zA, zAT);
  // pinv: 24 launches, 64x64-tile pgemm (128 blocks each), per-head XCD-grouped
  {
    bf* zc = zA; bf* zcT = zAT; bf* zn = zB; bf* znT = zBT;
    for (int it = 0; it < 6; ++it) {
      pgemm_k<1,1><<<dim3(4, 4, 8), 256, 0, stream>>>(Xbf, zcT, Gbf, TB0, 1.f, 7.f);
      pgemm_k<0,1><<<dim3(4, 4, 8), 256, 0, stream>>>(Gbf, TB0, nullptr, TB1, 1.f, 15.f);
      pgemm_k<0,1><<<dim3(4, 4, 8), 256, 0, stream>>>(Gbf, TB1, nullptr, TB0, 1.f, 13.f);
      pgemm_k<1,0><<<dim3(4, 4, 8), 256, 0, stream>>>(zc, TB0, zn, znT, 0.25f, 0.f);
      bf* t = zc; zc = zn; zn = t; t = zcT; zcT = znT; znT = t;
    }
  }
  // flash attn3 (16 key-chunks, per-head XCD-grouped) + parallel combine -> AVT
  attn3f_k<<<dim3(16, 2, 8), 256, 0, stream>>>(QLbf, Kbf, VT, Opart, Mpart, Lpart);
  attn3c_k<<<128, 256, 0, stream>>>(Opart, Mpart, Lpart, AVT);
  // CM^T = (Z @ AV)^T   (z ends at zA after 6 swaps)
  bgemm<6><<<dim3(1, 2, 8), 256, 0, stream>>>(zA, AVT, nullptr, CMT,
      64, 1.f, 0.f, 256, 256, 0, 256, 65536, 16384, 0, 16384);
  tconv_k<<<dim3(32, 8), 256, 0, stream>>>(w1, w1T, 512, 2048);
  tconv_k<<<dim3(8, 32), 256, 0, stream>>>(w2, w2T, 2048, 512);
  tconv_k<<<dim3(8, 8), 256, 0, stream>>>(wout, woutT, 512, 512);
  attn1_k<<<dim3(64, 8), 256, 0, stream>>>(Qbf, KLbf, CMT, Bhbf);
  convres_k<<<4096, 256, 0, stream>>>(Vbf, convw, Bhbf);
  gemm256<1><<<dim3(2, 32), 512, DLDS, stream>>>(Bhbf, woutT, A, A, bout, 512, 512,
      nullptr, nullptr, nullptr);
  ln_bf16_k<<<8192, 256, 0, stream>>>(A, ln2g, ln2b, ln2bf);
  gemm256<2><<<dim3(8, 32), 512, DLDS, stream>>>(ln2bf, w1T, FF1bf, nullptr, b1, 512, 2048,
      nullptr, nullptr, nullptr);
  gemm256<1><<<dim3(2, 32), 512, DLDS, stream>>>(FF1bf, w2T, out, A, b2, 2048, 512,
      nullptr, nullptr, nullptr);
}

// Round 13
// 458.330 us; speedup vs baseline: 1.1048x; 1.1048x over previous
//
#include <hip/hip_runtime.h>
#include <hip/hip_bf16.h>

typedef __attribute__((ext_vector_type(8))) short short8;
typedef __attribute__((ext_vector_type(4))) short short4v;
typedef __attribute__((ext_vector_type(4))) float f32x4;
typedef __hip_bfloat16 bf;

__device__ __forceinline__ void gl_lds16(const void* g, void* l) {
  __builtin_amdgcn_global_load_lds(
      (const __attribute__((address_space(1))) unsigned int*)g,
      (__attribute__((address_space(3))) unsigned int*)l, 16, 0, 0);
}
__device__ __forceinline__ unsigned short f2b(float f) {
  bf h = __float2bfloat16(f);
  return *reinterpret_cast<unsigned short*>(&h);
}
__device__ __forceinline__ float b2f(unsigned short u) {
  unsigned v = ((unsigned)u) << 16;
  return __uint_as_float(v);
}

// ---------------- fused concat + LN1 -> bf16 (also writes A f32) ----------------
__global__ __launch_bounds__(256) void concat_ln_k(const float* __restrict__ x,
    const float* __restrict__ cls, const float* __restrict__ g,
    const float* __restrict__ b, float* __restrict__ A, bf* __restrict__ O)
{
  __shared__ float red[256];
  const long row = blockIdx.x; const int tid = threadIdx.x;
  const float* src = (row == 0) ? cls : (x + (row - 1) * 512);
  float v0 = src[tid], v1 = src[tid + 256];
  A[row * 512 + tid] = v0; A[row * 512 + tid + 256] = v1;
  red[tid] = v0 + v1; __syncthreads();
  for (int s = 128; s > 0; s >>= 1) { if (tid < s) red[tid] += red[tid + s]; __syncthreads(); }
  float mean = red[0] * (1.f / 512.f); __syncthreads();
  float d0 = v0 - mean, d1 = v1 - mean;
  red[tid] = d0 * d0 + d1 * d1; __syncthreads();
  for (int s = 128; s > 0; s >>= 1) { if (tid < s) red[tid] += red[tid + s]; __syncthreads(); }
  float rs = rsqrtf(red[0] * (1.f / 512.f) + 1e-5f);
  O[row * 512 + tid]       = __float2bfloat16(d0 * rs * g[tid] + b[tid]);
  O[row * 512 + tid + 256] = __float2bfloat16(d1 * rs * g[tid + 256] + b[tid + 256]);
}

// ---------------- fused LN -> bf16 ----------------
__global__ __launch_bounds__(256) void ln_bf16_k(const float* __restrict__ X,
    const float* __restrict__ g, const float* __restrict__ b,
    bf* __restrict__ O)
{
  __shared__ float red[256];
  const long row = blockIdx.x; const int tid = threadIdx.x;
  const float* r = X + row * 512;
  float v0 = r[tid], v1 = r[tid + 256];
  red[tid] = v0 + v1; __syncthreads();
  for (int s = 128; s > 0; s >>= 1) { if (tid < s) red[tid] += red[tid + s]; __syncthreads(); }
  float mean = red[0] * (1.f / 512.f); __syncthreads();
  float d0 = v0 - mean, d1 = v1 - mean;
  red[tid] = d0 * d0 + d1 * d1; __syncthreads();
  for (int s = 128; s > 0; s >>= 1) { if (tid < s) red[tid] += red[tid + s]; __syncthreads(); }
  float rs = rsqrtf(red[0] * (1.f / 512.f) + 1e-5f);
  O[row * 512 + tid]       = __float2bfloat16(d0 * rs * g[tid] + b[tid]);
  O[row * 512 + tid + 256] = __float2bfloat16(d1 * rs * g[tid + 256] + b[tid + 256]);
}

// ---------------- weight transpose f32[K][N] -> bf16[N][K] ----------------
__global__ __launch_bounds__(256) void tconv_k(const float* __restrict__ W,
    bf* __restrict__ WT, int K, int N)
{
  __shared__ float t[64][65];
  const int n0 = blockIdx.x << 6, k0 = blockIdx.y << 6;
  const int c = threadIdx.x & 63; const int r4 = threadIdx.x >> 6;
  #pragma unroll 4
  for (int i = 0; i < 16; i++) {
    int r = r4 * 16 + i;
    t[r][c] = W[(long)(k0 + r) * N + n0 + c];
  }
  __syncthreads();
  #pragma unroll 4
  for (int i = 0; i < 16; i++) {
    int r = r4 * 16 + i;
    WT[(long)(n0 + r) * K + k0 + c] = __float2bfloat16(t[c][r]);
  }
}

// ---------------- double-buffered bf16 MFMA GEMM, XCD-swizzled: C = A @ B^T ----------------
// EPI: 1 = f32 + bias + residual; 2 = bf16 + bias + gelu; 3 = head-major Q/K/V bf16
template<int EPI>
__global__ __launch_bounds__(256) void gemm_bf(
    const bf* __restrict__ Ag, const bf* __restrict__ Bg,
    void* __restrict__ Cg, const float* __restrict__ Res,
    const float* __restrict__ bias, int K, int N,
    bf* __restrict__ Qb, bf* __restrict__ Kb, bf* __restrict__ Vb)
{
  __shared__ __align__(16) short As[2][2][128][32];
  __shared__ __align__(16) short Bs[2][2][128][32];
  const int tid = threadIdx.x, lane = tid & 63, wid = tid >> 6;
  // XCD-aware chunked swizzle: blocks sharing an A-row panel land on one XCD.
  const int nwg = gridDim.x * gridDim.y;
  const int lin = blockIdx.y * gridDim.x + blockIdx.x;
  const int nl = (lin & 7) * (nwg >> 3) + (lin >> 3);
  const int bxi = nl % gridDim.x, byi = nl / gridDim.x;
  const int brow = byi << 7, bcol = bxi << 7;
  const int wr = (wid >> 1) << 6, wc = (wid & 1) << 6;
  const int fr = lane & 15, fs = lane >> 4;
  const int srow = lane >> 2, skp = (lane & 3) << 3;
  f32x4 acc[4][4];
  #pragma unroll
  for (int m = 0; m < 4; m++)
    #pragma unroll
    for (int n = 0; n < 4; n++) acc[m][n] = (f32x4){0.f, 0.f, 0.f, 0.f};

  const bf* Arow = Ag + (long)brow * K;
  const bf* Brow = Bg + (long)bcol * K;

  auto stage = [&](int bufi, int koff) {
    #pragma unroll
    for (int i = 0; i < 4; i++) {
      int c = (wid << 2) + i, rg = c >> 1, hf = c & 1;
      gl_lds16(Arow + (long)(rg * 16 + srow) * K + koff + hf * 32 + skp,
               &As[bufi][hf][rg * 16][0]);
      gl_lds16(Brow + (long)(rg * 16 + srow) * K + koff + hf * 32 + skp,
               &Bs[bufi][hf][rg * 16][0]);
    }
  };

  stage(0, 0);
  __syncthreads();
  const int nk = K >> 6;
  for (int t = 0; t < nk; ++t) {
    const int buf = t & 1;
    if (t + 1 < nk) stage(buf ^ 1, (t + 1) << 6);
    #pragma unroll
    for (int kk = 0; kk < 2; kk++) {
      short8 a[4], b[4];
      #pragma unroll
      for (int m = 0; m < 4; m++)
        a[m] = *(const short8*)&As[buf][kk][wr + m * 16 + fr][fs * 8];
      #pragma unroll
      for (int n = 0; n < 4; n++)
        b[n] = *(const short8*)&Bs[buf][kk][wc + n * 16 + fr][fs * 8];
      #pragma unroll
      for (int m = 0; m < 4; m++)
        #pragma unroll
        for (int n = 0; n < 4; n++)
          acc[m][n] = __builtin_amdgcn_mfma_f32_16x16x32_bf16(a[m], b[n], acc[m][n], 0, 0, 0);
    }
    __syncthreads();
  }

  #pragma unroll
  for (int m = 0; m < 4; m++) {
    #pragma unroll
    for (int n = 0; n < 4; n++) {
      const int col = bcol + wc + n * 16 + fr;
      #pragma unroll
      for (int j = 0; j < 4; j++) {
        const long row = brow + wr + m * 16 + fs * 4 + j;
        float v = acc[m][n][j];
        if (EPI == 1) {
          v += bias[col] + Res[row * N + col];
          ((float*)Cg)[row * N + col] = v;
        } else if (EPI == 2) {
          v += bias[col];
          v = 0.5f * v * (1.f + erff(v * 0.70710678118654752f));
          ((bf*)Cg)[row * N + col] = __float2bfloat16(v);
        } else {
          int sect = col >> 9, h = (col >> 6) & 7, d = col & 63;
          long o = ((long)h * 8192 + row) * 64 + d;
          if (sect == 0)      Qb[o] = __float2bfloat16(v * 0.125f);
          else if (sect == 1) Kb[o] = __float2bfloat16(v);
          else                Vb[o] = __float2bfloat16(v);
        }
      }
    }
  }
}

// ---------------- pinv phase GEMM: 64x64 tiles, grid (4,4,8), XCD-swizzled per head ----------------
template<int CS, int DIAG>
__global__ __launch_bounds__(256) void pgemm_k(
    const bf* __restrict__ Ag, const bf* __restrict__ Bg,
    bf* __restrict__ Cg, bf* __restrict__ Tg, float alpha, float s)
{
  __shared__ __align__(16) short As[8][64][32];
  __shared__ __align__(16) short Bs[8][64][32];
  short (*Tt)[68] = (short(*)[68])&As[0][0][0];
  const int tid = threadIdx.x, lane = tid & 63, wid = tid >> 6;
  // chunked swizzle: each head's 16 blocks land on one XCD (nwg=128, q=16)
  const int lin = (blockIdx.z * 4 + blockIdx.y) * 4 + blockIdx.x;
  const int nl = (lin & 7) * 16 + (lin >> 3);
  const int bz = nl >> 4, rem = nl & 15;
  const long base = (long)bz << 16;
  const int brow = (rem >> 2) << 6, bcol = (rem & 3) << 6;
  const int wr = (wid >> 1) << 5, wc = (wid & 1) << 5;
  const int fr = lane & 15, fs = lane >> 4;
  const int srow = lane >> 2, skp = (lane & 3) << 3;
  const bf* Arow = Ag + base + (long)brow * 256;
  const bf* Brow = Bg + base + (long)bcol * 256;
  #pragma unroll
  for (int i = 0; i < 16; i++) {
    int c = (wid << 4) + i;
    int mat = c >> 5, c5 = c & 31, rg = c5 >> 3, ks = c5 & 7;
    const bf* src = (mat ? Brow : Arow) + (long)(rg * 16 + srow) * 256 + ks * 32 + skp;
    gl_lds16(src, mat ? &Bs[ks][rg * 16][0] : &As[ks][rg * 16][0]);
  }
  __syncthreads();
  f32x4 acc[2][2];
  #pragma unroll
  for (int m = 0; m < 2; m++)
    #pragma unroll
    for (int n = 0; n < 2; n++) acc[m][n] = (f32x4){0.f, 0.f, 0.f, 0.f};
  #pragma unroll
  for (int ks = 0; ks < 8; ks++) {
    short8 a[2], b[2];
    #pragma unroll
    for (int m = 0; m < 2; m++)
      a[m] = *(const short8*)&As[ks][wr + m * 16 + fr][fs * 8];
    #pragma unroll
    for (int n = 0; n < 2; n++)
      b[n] = *(const short8*)&Bs[ks][wc + n * 16 + fr][fs * 8];
    #pragma unroll
    for (int m = 0; m < 2; m++)
      #pragma unroll
      for (int n = 0; n < 2; n++)
        acc[m][n] = __builtin_amdgcn_mfma_f32_16x16x32_bf16(a[m], b[n], acc[m][n], 0, 0, 0);
  }
  if (CS) {
    #pragma unroll
    for (int m = 0; m < 2; m++)
      #pragma unroll
      for (int n = 0; n < 2; n++) {
        const int col = bcol + wc + n * 16 + fr;
        #pragma unroll
        for (int j = 0; j < 4; j++)
          (Cg + base)[(long)(brow + wr + m * 16 + fs * 4 + j) * 256 + col] =
              __float2bfloat16(acc[m][n][j] * alpha);
      }
  }
  __syncthreads();
  #pragma unroll
  for (int m = 0; m < 2; m++)
    #pragma unroll
    for (int n = 0; n < 2; n++) {
      const int lcol = wc + n * 16 + fr;
      #pragma unroll
      for (int j = 0; j < 4; j++) {
        const int lrow = wr + m * 16 + fs * 4 + j;
        float v = acc[m][n][j] * alpha;
        float o = DIAG ? (((brow + lrow) == (bcol + lcol)) ? (s - v) : (-v)) : v;
        Tt[lcol][lrow] = (short)f2b(o);
      }
    }
  __syncthreads();
  {
    const int lcol = tid >> 2, q = tid & 3;
    short8 w0 = *(const short8*)&Tt[lcol][q * 16];
    short8 w1 = *(const short8*)&Tt[lcol][q * 16 + 8];
    bf* dst = Tg + base + (long)(bcol + lcol) * 256 + brow + q * 16;
    *(short8*)dst = w0;
    *(short8*)(dst + 8) = w1;
  }
}

// ---------------- batched bf16 MFMA GEMM (CM only), K=256, dbuf ----------------
template<int EPI>
__global__ __launch_bounds__(256) void bgemm(
    const bf* __restrict__ Ag, const bf* __restrict__ Bg,
    void* __restrict__ Cg, bf* __restrict__ Tg,
    int Nc, float alpha, float s,
    long lda, long ldb, long ldc, long ldt,
    long sA, long sB, long sC, long sT)
{
  __shared__ __align__(16) short As[2][2][128][32];
  __shared__ __align__(16) short Bs[2][2][128][32];
  const int tid = threadIdx.x, lane = tid & 63, wid = tid >> 6;
  const int hh = blockIdx.z;
  const int brow = blockIdx.y << 7, bcol = blockIdx.x << 7;
  const int wr = (wid >> 1) << 6, wc = (wid & 1) << 6;
  const int fr = lane & 15, fs = lane >> 4;
  const int srow = lane >> 2, skp = (lane & 3) << 3;
  f32x4 acc[4][4];
  #pragma unroll
  for (int m = 0; m < 4; m++)
    #pragma unroll
    for (int n = 0; n < 4; n++) acc[m][n] = (f32x4){0.f, 0.f, 0.f, 0.f};

  const bf* Arow = Ag + hh * sA + (long)brow * lda;
  const bf* Brow = Bg + hh * sB + (long)bcol * ldb;

  auto stage = [&](int bufi, int koff) {
    #pragma unroll
    for (int i = 0; i < 4; i++) {
      int c = (wid << 2) + i, rg = c >> 1, hf = c & 1;
      gl_lds16(Arow + (long)(rg * 16 + srow) * lda + koff + hf * 32 + skp,
               &As[bufi][hf][rg * 16][0]);
      gl_lds16(Brow + (long)(rg * 16 + srow) * ldb + koff + hf * 32 + skp,
               &Bs[bufi][hf][rg * 16][0]);
    }
  };

  stage(0, 0);
  __syncthreads();
  #pragma unroll
  for (int t = 0; t < 4; ++t) {
    const int buf = t & 1;
    if (t < 3) stage(buf ^ 1, (t + 1) << 6);
    #pragma unroll
    for (int kk = 0; kk < 2; kk++) {
      short8 a[4], b[4];
      #pragma unroll
      for (int m = 0; m < 4; m++)
        a[m] = *(const short8*)&As[buf][kk][wr + m * 16 + fr][fs * 8];
      #pragma unroll
      for (int n = 0; n < 4; n++)
        b[n] = *(const short8*)&Bs[buf][kk][wc + n * 16 + fr][fs * 8];
      #pragma unroll
      for (int m = 0; m < 4; m++)
        #pragma unroll
        for (int n = 0; n < 4; n++)
          acc[m][n] = __builtin_amdgcn_mfma_f32_16x16x32_bf16(a[m], b[n], acc[m][n], 0, 0, 0);
    }
    __syncthreads();
  }

  #pragma unroll
  for (int m = 0; m < 4; m++) {
    #pragma unroll
    for (int n = 0; n < 4; n++) {
      const int col = bcol + wc + n * 16 + fr;
      const int rbase = brow + wr + m * 16 + fs * 4;
      if (EPI != 6 || col < Nc) {
        bf* Tb = Tg + hh * sT;
        short4v tv;
        #pragma unroll
        for (int j = 0; j < 4; j++) tv[j] = (short)f2b(acc[m][n][j] * alpha);
        *(short4v*)&Tb[(long)col * ldt + rbase] = tv;
      }
    }
  }
}

// ---------------- fp32 tiled GEMM (attn2 logits only) ----------------
__global__ __launch_bounds__(256) void sgemm_k(
    const float* __restrict__ A, const float* __restrict__ Bw,
    float* __restrict__ C,
    int K, long lda, long ldb, long ldc,
    long sA, long sB, long sC)
{
  __shared__ float As[16][68];
  __shared__ __align__(16) float Bs[16][68];
  const int tid = threadIdx.x;
  const int zz = blockIdx.z;
  const float* Ab = A + zz * sA;
  const float* Bb = Bw + zz * sB;
  float* Cb = C + zz * sC;
  const int brow = blockIdx.y * 64;
  const int bcol = blockIdx.x * 64;
  const int tm = tid >> 4, tn = tid & 15;
  const int lam = tid >> 2;
  const int lak = (tid & 3) << 2;
  const int lbk = tid >> 4;
  const int lbn = (tid & 15) << 2;
  float acc[4][4];
  #pragma unroll
  for (int i = 0; i < 4; i++)
    #pragma unroll
    for (int j = 0; j < 4; j++) acc[i][j] = 0.f;

  for (int k0 = 0; k0 < K; k0 += 16) {
    float4 av = *(const float4*)&Ab[(long)(brow + lam) * lda + k0 + lak];
    As[lak + 0][lam] = av.x; As[lak + 1][lam] = av.y;
    As[lak + 2][lam] = av.z; As[lak + 3][lam] = av.w;
    float4 bv = *(const float4*)&Bb[(long)(k0 + lbk) * ldb + bcol + lbn];
    *(float4*)&Bs[lbk][lbn] = bv;
    __syncthreads();
    #pragma unroll
    for (int kk = 0; kk < 16; kk++) {
      float a0 = As[kk][(tm << 2) + 0], a1 = As[kk][(tm << 2) + 1];
      float a2 = As[kk][(tm << 2) + 2], a3 = As[kk][(tm << 2) + 3];
      float b0 = Bs[kk][(tn << 2) + 0], b1 = Bs[kk][(tn << 2) + 1];
      float b2 = Bs[kk][(tn << 2) + 2], b3 = Bs[kk][(tn << 2) + 3];
      acc[0][0] += a0 * b0; acc[0][1] += a0 * b1; acc[0][2] += a0 * b2; acc[0][3] += a0 * b3;
      acc[1][0] += a1 * b0; acc[1][1] += a1 * b1; acc[1][2] += a1 * b2; acc[1][3] += a1 * b3;
      acc[2][0] += a2 * b0; acc[2][1] += a2 * b1; acc[2][2] += a2 * b2; acc[2][3] += a2 * b3;
      acc[3][0] += a3 * b0; acc[3][1] += a3 * b1; acc[3][2] += a3 * b2; acc[3][3] += a3 * b3;
    }
    __syncthreads();
  }
  #pragma unroll
  for (int i = 0; i < 4; i++) {
    const long row = brow + (tm << 2) + i;
    #pragma unroll
    for (int j = 0; j < 4; j++) {
      const int col = bcol + (tn << 2) + j;
      Cb[row * ldc + col] = acc[i][j];
    }
  }
}

// ---------------- landmarks from bf16 Q/K ----------------
__global__ __launch_bounds__(256) void landmarks_k(const bf* __restrict__ Qb,
    const bf* __restrict__ Kb,
    float* __restrict__ QL, float* __restrict__ KLT,
    bf* __restrict__ QLb, bf* __restrict__ KLb)
{
  int t = blockIdx.x * 256 + threadIdx.x;
  int d = t & 63; int m = (t >> 6) & 255; int h = t >> 14;
  const unsigned short* qp = (const unsigned short*)Qb + ((long)h * 8192 + m * 32) * 64 + d;
  const unsigned short* kp = (const unsigned short*)Kb + ((long)h * 8192 + m * 32) * 64 + d;
  float sq = 0.f, sk = 0.f;
  for (int i = 0; i < 32; i++) { sq += b2f(qp[i * 64]); sk += b2f(kp[i * 64]); }
  float qv = sq * (1.f / 32.f);
  QL[t] = qv;
  QLb[t] = __float2bfloat16(qv);
  float kv = sk * (1.f / 32.f);
  KLb[t] = __float2bfloat16(kv);
  KLT[(h << 14) + (d << 8) + m] = kv;
}

// ---------------- V transpose (bf16 -> bf16): VT[h][d][n] ----------------
__global__ __launch_bounds__(256) void vt_k(const bf* __restrict__ Vb,
    bf* __restrict__ VT)
{
  __shared__ unsigned short t[64][68];
  const int h = blockIdx.x & 7; const int n0 = (blockIdx.x >> 3) << 6;
  const int c = threadIdx.x & 63; const int r4 = threadIdx.x >> 6;
  const unsigned short* vp = (const unsigned short*)Vb;
  unsigned short* vo = (unsigned short*)VT;
  #pragma unroll 4
  for (int i = 0; i < 16; i++) {
    int r = r4 * 16 + i;
    t[r][c] = vp[((long)h * 8192 + n0 + r) * 64 + c];
  }
  __syncthreads();
  #pragma unroll 4
  for (int i = 0; i < 16; i++) {
    int d = r4 * 16 + i;
    vo[((long)(h << 6) + d) * 8192 + n0 + c] = t[c][d];
  }
}

// ---------------- row softmax, width 256, f32 in place ----------------
__global__ __launch_bounds__(256) void softmax256_k(float* __restrict__ X)
{
  __shared__ float red[256];
  const long row = blockIdx.x; const int tid = threadIdx.x;
  float v = X[row * 256 + tid];
  red[tid] = v; __syncthreads();
  for (int s = 128; s > 0; s >>= 1) { if (tid < s) red[tid] = fmaxf(red[tid], red[tid + s]); __syncthreads(); }
  float M = red[0]; __syncthreads();
  float e = __expf(v - M);
  red[tid] = e; __syncthreads();
  for (int s = 128; s > 0; s >>= 1) { if (tid < s) red[tid] += red[tid + s]; __syncthreads(); }
  float S = red[0];
  X[row * 256 + tid] = e / S;
}

// ---------------- pinv scalars ----------------
__global__ __launch_bounds__(256) void colsum_k(const float* __restrict__ X, float* __restrict__ out)
{
  int t = blockIdx.x * 256 + threadIdx.x; int h = t >> 8; int j = t & 255;
  const float* c = X + ((long)h << 16) + j;
  float s = 0.f;
  for (int i = 0; i < 256; i++) s += fabsf(c[(long)i << 8]);
  out[t] = s;
}
__global__ __launch_bounds__(256) void invscale_k(const float* __restrict__ cols,
    float* __restrict__ inv)
{
  __shared__ float red[256];
  int tid = threadIdx.x;
  float mc = -1e30f;
  for (int i = tid; i < 2048; i += 256) mc = fmaxf(mc, cols[i]);
  red[tid] = mc; __syncthreads();
  for (int s = 128; s > 0; s >>= 1) { if (tid < s) red[tid] = fmaxf(red[tid], red[tid + s]); __syncthreads(); }
  if (tid == 0) inv[0] = 1.0f / red[0];
}

// ---------------- pinv init: Xbf, z0 = X^T*inv, z0T = X*inv ----------------
__global__ __launch_bounds__(256) void xz_init_k(const float* __restrict__ ATT2,
    const float* __restrict__ inv, bf* __restrict__ Xb,
    bf* __restrict__ z0, bf* __restrict__ z0T)
{
  __shared__ float t[64][65];
  const int h = blockIdx.z;
  const int j0 = blockIdx.x << 6, i0 = blockIdx.y << 6;
  const int c = threadIdx.x & 63; const int r4 = threadIdx.x >> 6;
  const float iv = inv[0];
  #pragma unroll 4
  for (int i = 0; i < 16; i++) {
    int r = r4 * 16 + i;
    float v = ATT2[((long)h << 16) + (long)(i0 + r) * 256 + j0 + c];
    t[r][c] = v;
    Xb[((long)h << 16) + (long)(i0 + r) * 256 + j0 + c]  = __float2bfloat16(v);
    z0T[((long)h << 16) + (long)(i0 + r) * 256 + j0 + c] = __float2bfloat16(v * iv);
  }
  __syncthreads();
  #pragma unroll 4
  for (int i = 0; i < 16; i++) {
    int r = r4 * 16 + i;
    z0[((long)h << 16) + (long)(j0 + r) * 256 + i0 + c] = __float2bfloat16(t[c][r] * iv);
  }
}

// ---------------- flash attn3, XCD-swizzled per head ----------------
__global__ __launch_bounds__(256) void attn3f_k(
    const bf* __restrict__ Qlb, const bf* __restrict__ Kb, const bf* __restrict__ Vt,
    float* __restrict__ Op, float* __restrict__ Mp, float* __restrict__ Lp)
{
  __shared__ __align__(16) short Qs[2][128][32];
  __shared__ __align__(16) short Ks[2][128][32];
  __shared__ __align__(16) short Vs[4][64][32];
  __shared__ __align__(16) short Ps[4][4][32][32];
  const int tid = threadIdx.x, lane = tid & 63, wid = tid >> 6;
  const int fr = lane & 15, fs = lane >> 4;
  const int srow = lane >> 2, skp = (lane & 3) << 3;
  // grid (16,2,8): chunked swizzle keeps each head's 32 blocks on one XCD
  const int lin = (blockIdx.z * 2 + blockIdx.y) * 16 + blockIdx.x;
  const int nl = (lin & 7) * 32 + (lin >> 3);
  const int chunk = nl & 15, mt = (nl >> 4) & 1, h = nl >> 5;
  const int wrb = wid << 5;
  const bf* Qg = Qlb + ((long)h * 256 + mt * 128) * 64;
  #pragma unroll
  for (int i = 0; i < 4; i++) {
    int c = (wid << 2) + i, rg = c >> 1, hf = c & 1;
    gl_lds16(Qg + (long)(rg * 16 + srow) * 64 + hf * 32 + skp, &Qs[hf][rg * 16][0]);
  }
  f32x4 acc2[2][4];
  float mrun[2][4], lrun[2][4];
  #pragma unroll
  for (int m = 0; m < 2; m++)
    #pragma unroll
    for (int n = 0; n < 4; n++) { acc2[m][n] = (f32x4){0.f,0.f,0.f,0.f}; mrun[m][n] = -1e30f; lrun[m][n] = 0.f; }

  for (int t = 0; t < 4; t++) {
    const int key0 = (chunk << 9) + (t << 7);
    const bf* Kg = Kb + ((long)h * 8192 + key0) * 64;
    #pragma unroll
    for (int i = 0; i < 4; i++) {
      int c = (wid << 2) + i, rg = c >> 1, hf = c & 1;
      gl_lds16(Kg + (long)(rg * 16 + srow) * 64 + hf * 32 + skp, &Ks[hf][rg * 16][0]);
    }
    #pragma unroll
    for (int i = 0; i < 4; i++) {
      int c = (wid << 2) + i, dg = c >> 2, ks = c & 3;
      gl_lds16(Vt + ((long)h * 64 + dg * 16 + srow) * 8192 + key0 + ks * 32 + skp,
               &Vs[ks][dg * 16][0]);
    }
    __syncthreads();
    f32x4 lac[2][8];
    #pragma unroll
    for (int m = 0; m < 2; m++)
      #pragma unroll
      for (int n = 0; n < 8; n++) lac[m][n] = (f32x4){0.f,0.f,0.f,0.f};
    #pragma unroll
    for (int kk = 0; kk < 2; kk++) {
      short8 a[2];
      #pragma unroll
      for (int m = 0; m < 2; m++)
        a[m] = *(const short8*)&Qs[kk][wrb + m * 16 + fr][fs * 8];
      #pragma unroll
      for (int n = 0; n < 8; n++) {
        short8 b = *(const short8*)&Ks[kk][n * 16 + fr][fs * 8];
        #pragma unroll
        for (int m = 0; m < 2; m++)
          lac[m][n] = __builtin_amdgcn_mfma_f32_16x16x32_bf16(a[m], b, lac[m][n], 0, 0, 0);
      }
    }
    #pragma unroll
    for (int m = 0; m < 2; m++) {
      #pragma unroll
      for (int j = 0; j < 4; j++) {
        float tmax = lac[m][0][j];
        #pragma unroll
        for (int n = 1; n < 8; n++) tmax = fmaxf(tmax, lac[m][n][j]);
        tmax = fmaxf(tmax, __shfl_xor(tmax, 1));
        tmax = fmaxf(tmax, __shfl_xor(tmax, 2));
        tmax = fmaxf(tmax, __shfl_xor(tmax, 4));
        tmax = fmaxf(tmax, __shfl_xor(tmax, 8));
        float mnew = fmaxf(mrun[m][j], tmax);
        float sc = __expf(mrun[m][j] - mnew);
        #pragma unroll
        for (int n2 = 0; n2 < 4; n2++) acc2[m][n2][j] *= sc;
        float lsum = 0.f;
        #pragma unroll
        for (int n = 0; n < 8; n++) {
          float p = __expf(lac[m][n][j] - mnew);
          lac[m][n][j] = p; lsum += p;
        }
        lsum += __shfl_xor(lsum, 1);
        lsum += __shfl_xor(lsum, 2);
        lsum += __shfl_xor(lsum, 4);
        lsum += __shfl_xor(lsum, 8);
        lrun[m][j] = lrun[m][j] * sc + lsum;
        mrun[m][j] = mnew;
      }
    }
    #pragma unroll
    for (int m = 0; m < 2; m++)
      #pragma unroll
      for (int n = 0; n < 8; n++) {
        int col = n * 16 + fr;
        #pragma unroll
        for (int j = 0; j < 4; j++)
          Ps[wid][col >> 5][m * 16 + fs * 4 + j][col & 31] = (short)f2b(lac[m][n][j]);
      }
    #pragma unroll
    for (int ks = 0; ks < 4; ks++) {
      short8 a2[2];
      #pragma unroll
      for (int m = 0; m < 2; m++)
        a2[m] = *(const short8*)&Ps[wid][ks][m * 16 + fr][fs * 8];
      #pragma unroll
      for (int n = 0; n < 4; n++) {
        short8 b2 = *(const short8*)&Vs[ks][n * 16 + fr][fs * 8];
        #pragma unroll
        for (int m = 0; m < 2; m++)
          acc2[m][n] = __builtin_amdgcn_mfma_f32_16x16x32_bf16(a2[m], b2, acc2[m][n], 0, 0, 0);
      }
    }
    __syncthreads();
  }
  const long base = (long)(chunk * 8 + h) * 2 + mt;
  #pragma unroll
  for (int m = 0; m < 2; m++)
    #pragma unroll
    for (int n = 0; n < 4; n++) {
      int col = n * 16 + fr;
      #pragma unroll
      for (int j = 0; j < 4; j++)
        Op[base * 8192 + (long)(wrb + m * 16 + fs * 4 + j) * 64 + col] = acc2[m][n][j];
    }
  if (fr == 0) {
    #pragma unroll
    for (int m = 0; m < 2; m++)
      #pragma unroll
      for (int j = 0; j < 4; j++) {
        int r = wrb + m * 16 + fs * 4 + j;
        Mp[base * 128 + r] = mrun[m][j];
        Lp[base * 128 + r] = lrun[m][j];
      }
  }
}

// ---------------- flash attn3 combine (parallel, 128 blocks) -> AVT bf16 [h][d][m] ----------------
__global__ __launch_bounds__(256) void attn3c_k(
    const float* __restrict__ Op, const float* __restrict__ Mp,
    const float* __restrict__ Lp, bf* __restrict__ AVT)
{
  __shared__ float wm[16][16];
  __shared__ float wl[16][16];
  const int bid = blockIdx.x;
  const int h = bid >> 4, mt = (bid >> 3) & 1, rs = bid & 7;
  const int tid = threadIdx.x;
  const int r0 = rs * 16;
  {
    int c = tid >> 4, r = tid & 15;
    long idx = ((long)(c * 8 + h) * 2 + mt) * 128 + r0 + r;
    wm[c][r] = Mp[idx];
    wl[c][r] = Lp[idx];
  }
  __syncthreads();
  if (tid < 16) {
    int r = tid;
    float M = wm[0][r];
    #pragma unroll
    for (int c = 1; c < 16; c++) M = fmaxf(M, wm[c][r]);
    float D = 0.f;
    #pragma unroll
    for (int c = 0; c < 16; c++) D += __expf(wm[c][r] - M) * wl[c][r];
    float rv = 1.0f / D;
    #pragma unroll
    for (int c = 0; c < 16; c++) wm[c][r] = __expf(wm[c][r] - M) * rv;
  }
  __syncthreads();
  #pragma unroll
  for (int i = 0; i < 4; i++) {
    int idx = i * 256 + tid;
    int r = idx >> 6, d = idx & 63;
    float s = 0.f;
    #pragma unroll
    for (int c = 0; c < 16; c++)
      s += wm[c][r] * Op[((long)(c * 8 + h) * 2 + mt) * 8192 + (long)(r0 + r) * 64 + d];
    AVT[(long)h * 16384 + d * 256 + mt * 128 + r0 + r] = __float2bfloat16(s);
  }
}

// ---------------- fused attn1: logits -> softmax -> @CM -> Bhbf ----------------
__global__ __launch_bounds__(256) void attn1_k(
    const bf* __restrict__ Qb, const bf* __restrict__ KLb,
    const bf* __restrict__ CMT, bf* __restrict__ Bhb)
{
  __shared__ __align__(16) char U[65536];
  short (*As)[128][32] = (short(*)[128][32])U;
  short (*Bs)[256][32] = (short(*)[256][32])(U + 16384);
  short (*Ps)[128][32] = (short(*)[128][32])U;
  __shared__ __align__(16) short Cs[8][64][32];
  __shared__ float red[2][2][128];

  const int tid = threadIdx.x;
  const int lane = tid & 63, wid = tid >> 6;
  const int fr = lane & 15, fs = lane >> 4;
  const int srow = lane >> 2, skp = (lane & 3) << 3;
  const int n0 = blockIdx.x << 7, h = blockIdx.y;
  const int half = wid & 1, wrb = (wid >> 1) << 6;

  const bf* Aq = Qb  + (long)h * 524288 + (long)n0 * 64;
  const bf* Bk = KLb + (long)h * 16384;
  const bf* Cm = CMT + (long)h * 16384;

  for (int i = 0; i < 20; i++) {
    int c = wid * 20 + i;
    if (c < 16) {
      int rg = c >> 1, hf = c & 1;
      gl_lds16(Aq + (long)(rg * 16 + srow) * 64 + hf * 32 + skp, &As[hf][rg * 16][0]);
    } else if (c < 48) {
      int c2 = c - 16; int rg = c2 >> 1, hf = c2 & 1;
      gl_lds16(Bk + (long)(rg * 16 + srow) * 64 + hf * 32 + skp, &Bs[hf][rg * 16][0]);
    } else {
      int c3 = c - 48; int rg = c3 >> 3, ks = c3 & 7;
      gl_lds16(Cm + (long)(rg * 16 + srow) * 256 + ks * 32 + skp, &Cs[ks][rg * 16][0]);
    }
  }
  __syncthreads();

  f32x4 acc[4][8];
  #pragma unroll
  for (int m = 0; m < 4; m++)
    #pragma unroll
    for (int n = 0; n < 8; n++) acc[m][n] = (f32x4){0.f, 0.f, 0.f, 0.f};
  #pragma unroll
  for (int kk = 0; kk < 2; kk++) {
    short8 a[4];
    #pragma unroll
    for (int m = 0; m < 4; m++)
      a[m] = *(const short8*)&As[kk][wrb + m * 16 + fr][fs * 8];
    #pragma unroll
    for (int n = 0; n < 8; n++) {
      short8 b = *(const short8*)&Bs[kk][half * 128 + n * 16 + fr][fs * 8];
      #pragma unroll
      for (int m = 0; m < 4; m++)
        acc[m][n] = __builtin_amdgcn_mfma_f32_16x16x32_bf16(a[m], b, acc[m][n], 0, 0, 0);
    }
  }

  #pragma unroll
  for (int m = 0; m < 4; m++)
    #pragma unroll
    for (int j = 0; j < 4; j++) {
      float mx = -1e30f;
      #pragma unroll
      for (int n = 0; n < 8; n++) mx = fmaxf(mx, acc[m][n][j]);
      mx = fmaxf(mx, __shfl_xor(mx, 1));
      mx = fmaxf(mx, __shfl_xor(mx, 2));
      mx = fmaxf(mx, __shfl_xor(mx, 4));
      mx = fmaxf(mx, __shfl_xor(mx, 8));
      int rloc = wrb + m * 16 + fs * 4 + j;
      if (fr == 0) red[0][half][rloc] = mx;
    }
  __syncthreads();
  #pragma unroll
  for (int m = 0; m < 4; m++)
    #pragma unroll
    for (int j = 0; j < 4; j++) {
      int rloc = wrb + m * 16 + fs * 4 + j;
      float Mx = fmaxf(red[0][0][rloc], red[0][1][rloc]);
      float s = 0.f;
      #pragma unroll
      for (int n = 0; n < 8; n++) {
        float e = __expf(acc[m][n][j] - Mx);
        acc[m][n][j] = e; s += e;
      }
      s += __shfl_xor(s, 1);
      s += __shfl_xor(s, 2);
      s += __shfl_xor(s, 4);
      s += __shfl_xor(s, 8);
      if (fr == 0) red[1][half][rloc] = s;
    }
  __syncthreads();
  #pragma unroll
  for (int m = 0; m < 4; m++)
    #pragma unroll
    for (int j = 0; j < 4; j++) {
      int rloc = wrb + m * 16 + fs * 4 + j;
      float inv = 1.0f / (red[1][0][rloc] + red[1][1][rloc]);
      #pragma unroll
      for (int n = 0; n < 8; n++) {
        int col = half * 128 + n * 16 + fr;
        Ps[col >> 5][rloc][col & 31] = (short)f2b(acc[m][n][j] * inv);
      }
    }
  __syncthreads();

  f32x4 acc2[4][2];
  #pragma unroll
  for (int m = 0; m < 4; m++)
    #pragma unroll
    for (int n = 0; n < 2; n++) acc2[m][n] = (f32x4){0.f, 0.f, 0.f, 0.f};
  const int wc2 = half * 32;
  #pragma unroll
  for (int kk = 0; kk < 8; kk++) {
    short8 a2[4];
    #pragma unroll
    for (int m = 0; m < 4; m++)
      a2[m] = *(const short8*)&Ps[kk][wrb + m * 16 + fr][fs * 8];
    #pragma unroll
    for (int n = 0; n < 2; n++) {
      short8 b2 = *(const short8*)&Cs[kk][wc2 + n * 16 + fr][fs * 8];
      #pragma unroll
      for (int m = 0; m < 4; m++)
        acc2[m][n] = __builtin_amdgcn_mfma_f32_16x16x32_bf16(a2[m], b2, acc2[m][n], 0, 0, 0);
    }
  }
  #pragma unroll
  for (int m = 0; m < 4; m++)
    #pragma unroll
    for (int n = 0; n < 2; n++) {
      int col = wc2 + n * 16 + fr;
      #pragma unroll
      for (int j = 0; j < 4; j++) {
        long row = n0 + wrb + m * 16 + fs * 4 + j;
        Bhb[row * 512 + h * 64 + col] = __float2bfloat16(acc2[m][n][j]);
      }
    }
}

// ---------------- depthwise conv residual, bf16 RMW into Bhbf ----------------
__global__ __launch_bounds__(256) void convres_k(const bf* __restrict__ Vb,
    const float* __restrict__ W, bf* __restrict__ Bhb)
{
  const int gid = blockIdx.x * 256 + threadIdx.x;
  const int n = gid >> 7, q = gid & 127;
  const int j0 = q << 2, h = j0 >> 6, d0 = j0 & 63;
  float a0 = 0.f, a1 = 0.f, a2 = 0.f, a3 = 0.f;
  const unsigned short* vb = (const unsigned short*)Vb + (long)h * 524288 + d0;
  #pragma unroll
  for (int kk = 0; kk < 33; kk++) {
    int nn = n + kk - 16;
    if (nn >= 0 && nn < 8192) {
      float w = W[h * 33 + kk];
      uint2 raw = *(const uint2*)(vb + (long)nn * 64);
      a0 += w * b2f(raw.x & 0xffff); a1 += w * b2f(raw.x >> 16);
      a2 += w * b2f(raw.y & 0xffff); a3 += w * b2f(raw.y >> 16);
    }
  }
  unsigned short* o = (unsigned short*)Bhb + (long)n * 512 + j0;
  uint2 cur = *(uint2*)o;
  uint2 outv;
  outv.x = (unsigned)f2b(b2f(cur.x & 0xffff) + a0) | ((unsigned)f2b(b2f(cur.x >> 16) + a1) << 16);
  outv.y = (unsigned)f2b(b2f(cur.y & 0xffff) + a2) | ((unsigned)f2b(b2f(cur.y >> 16) + a3) << 16);
  *(uint2*)o = outv;
}

// ---------------- host ----------------
extern "C" void kernel_launch(void* const* d_in, const int* in_sizes, int n_in,
                              void* d_out, int out_size, void* d_ws, size_t ws_size,
                              hipStream_t stream)
{
  const float* x     = (const float*)d_in[0];
  const float* cls   = (const float*)d_in[1];
  const float* ln1g  = (const float*)d_in[2];
  const float* ln1b  = (const float*)d_in[3];
  const float* wqkv  = (const float*)d_in[4];
  const float* wout  = (const float*)d_in[5];
  const float* bout  = (const float*)d_in[6];
  const float* convw = (const float*)d_in[7];
  const float* ln2g  = (const float*)d_in[8];
  const float* ln2b  = (const float*)d_in[9];
  const float* w1    = (const float*)d_in[10];
  const float* b1    = (const float*)d_in[11];
  const float* w2    = (const float*)d_in[12];
  const float* b2    = (const float*)d_in[13];
  float* out = (float*)d_out;
  float* ws  = (float*)d_ws;

  float* A     = ws + 0;              // [8192][512] f32
  float* QL    = ws + 4194304;
  float* KLT   = ws + 4325376;
  float* ATT2  = ws + 4456448;
  float* csum  = ws + 4980736;
  float* inv   = ws + 4982784;        // 8
  float* Opart = ws + 4982800;        // [16][8][2][128][64] f32
  float* Mpart = ws + 7079952;        // [16][8][2][128]
  float* Lpart = ws + 7112720;
  bf* Qbf  = (bf*)(ws + 7145488);     // [8][8192][64] prescaled 0.125
  bf* Kbf  = (bf*)(ws + 9242640);
  bf* Vbf  = (bf*)(ws + 11339792);
  bf* VT   = (bf*)(ws + 13436944);    // [8][64][8192]
  bf* QLbf = (bf*)(ws + 15534096);
  bf* KLbf = (bf*)(ws + 15599632);
  bf* Xbf  = (bf*)(ws + 15665168);    // [8][256][256]
  bf* zA   = (bf*)(ws + 15927312);
  bf* zAT  = (bf*)(ws + 16189456);
  bf* zB   = (bf*)(ws + 16451600);
  bf* zBT  = (bf*)(ws + 16713744);
  bf* Gbf  = (bf*)(ws + 16975888);
  bf* TB0  = (bf*)(ws + 17238032);
  bf* TB1  = (bf*)(ws + 17500176);
  bf* AVT  = (bf*)(ws + 17762320);    // [8][64][256]
  bf* CMT  = (bf*)(ws + 17827856);
  float* R = ws + 17893392;           // reusable region
  bf* wqkvT = (bf*)R;                 // [1536][512]
  bf* ln1bf = (bf*)(R + 393216);      // [8192][512]
  bf* Bhbf  = (bf*)(R + 393216);      // aliases ln1bf after it dies
  bf* FF1bf = (bf*)R;                 // [8192][2048] after wqkvT/Bhbf dead
  bf* w1T   = Kbf;                    // aliases (Kbf dead after attn3f)
  bf* w2T   = Kbf + 1048576;
  bf* woutT = Kbf + 2097152;
  bf* ln2bf = VT;                     // aliases (VT dead after attn3f)

  concat_ln_k<<<8192, 256, 0, stream>>>(x, cls, ln1g, ln1b, A, ln1bf);
  tconv_k<<<dim3(24, 8), 256, 0, stream>>>(wqkv, wqkvT, 512, 1536);
  gemm_bf<3><<<dim3(12, 64), 256, 0, stream>>>(ln1bf, wqkvT, nullptr, nullptr, nullptr,
      512, 1536, Qbf, Kbf, Vbf);
  landmarks_k<<<512, 256, 0, stream>>>(Qbf, Kbf, QL, KLT, QLbf, KLbf);
  vt_k<<<1024, 256, 0, stream>>>(Vbf, VT);
  sgemm_k<<<dim3(4, 4, 8), 256, 0, stream>>>(QL, KLT, ATT2,
      64, 64, 256, 256, 16384, 16384, 65536);
  softmax256_k<<<2048, 256, 0, stream>>>(ATT2);
  colsum_k<<<8, 256, 0, stream>>>(ATT2, csum);
  invscale_k<<<1, 256, 0, stream>>>(csum, inv);
  xz_init_k<<<dim3(4, 4, 8), 256, 0, stream>>>(ATT2, inv, Xbf, zA, zAT);
  // pinv: 24 launches, 64x64-tile pgemm (128 blocks each), per-head XCD-grouped
  {
    bf* zc = zA; bf* zcT = zAT; bf* zn = zB; bf* znT = zBT;
    for (int it = 0; it < 6; ++it) {
      pgemm_k<1,1><<<dim3(4, 4, 8), 256, 0, stream>>>(Xbf, zcT, Gbf, TB0, 1.f, 7.f);
      pgemm_k<0,1><<<dim3(4, 4, 8), 256, 0, stream>>>(Gbf, TB0, nullptr, TB1, 1.f, 15.f);
      pgemm_k<0,1><<<dim3(4, 4, 8), 256, 0, stream>>>(Gbf, TB1, nullptr, TB0, 1.f, 13.f);
      pgemm_k<1,0><<<dim3(4, 4, 8), 256, 0, stream>>>(zc, TB0, zn, znT, 0.25f, 0.f);
      bf* t = zc; zc = zn; zn = t; t = zcT; zcT = znT; znT = t;
    }
  }
  // flash attn3 (16 key-chunks, per-head XCD-grouped) + parallel combine -> AVT
  attn3f_k<<<dim3(16, 2, 8), 256, 0, stream>>>(QLbf, Kbf, VT, Opart, Mpart, Lpart);
  attn3c_k<<<128, 256, 0, stream>>>(Opart, Mpart, Lpart, AVT);
  // CM^T = (Z @ AV)^T   (z ends at zA after 6 swaps)
  bgemm<6><<<dim3(1, 2, 8), 256, 0, stream>>>(zA, AVT, nullptr, CMT,
      64, 1.f, 0.f, 256, 256, 0, 256, 65536, 16384, 0, 16384);
  tconv_k<<<dim3(32, 8), 256, 0, stream>>>(w1, w1T, 512, 2048);
  tconv_k<<<dim3(8, 32), 256, 0, stream>>>(w2, w2T, 2048, 512);
  tconv_k<<<dim3(8, 8), 256, 0, stream>>>(wout, woutT, 512, 512);
  attn1_k<<<dim3(64, 8), 256, 0, stream>>>(Qbf, KLbf, CMT, Bhbf);
  convres_k<<<4096, 256, 0, stream>>>(Vbf, convw, Bhbf);
  gemm_bf<1><<<dim3(4, 64), 256, 0, stream>>>(Bhbf, woutT, A, A, bout, 512, 512,
      nullptr, nullptr, nullptr);
  ln_bf16_k<<<8192, 256, 0, stream>>>(A, ln2g, ln2b, ln2bf);
  gemm_bf<2><<<dim3(16, 64), 256, 0, stream>>>(ln2bf, w1T, FF1bf, nullptr, b1, 512, 2048,
      nullptr, nullptr, nullptr);
  gemm_bf<1><<<dim3(4, 64), 256, 0, stream>>>(FF1bf, w2T, out, A, b2, 2048, 512,
      nullptr, nullptr, nullptr);
}

// Round 14
// 454.509 us; speedup vs baseline: 1.1141x; 1.0084x over previous
//
#include <hip/hip_runtime.h>
#include <hip/hip_bf16.h>

typedef __attribute__((ext_vector_type(8))) short short8;
typedef __attribute__((ext_vector_type(4))) short short4v;
typedef __attribute__((ext_vector_type(4))) float f32x4;
typedef __hip_bfloat16 bf;

__device__ __forceinline__ void gl_lds16(const void* g, void* l) {
  __builtin_amdgcn_global_load_lds(
      (const __attribute__((address_space(1))) unsigned int*)g,
      (__attribute__((address_space(3))) unsigned int*)l, 16, 0, 0);
}
__device__ __forceinline__ unsigned short f2b(float f) {
  bf h = __float2bfloat16(f);
  return *reinterpret_cast<unsigned short*>(&h);
}
__device__ __forceinline__ float b2f(unsigned short u) {
  unsigned v = ((unsigned)u) << 16;
  return __uint_as_float(v);
}

// ---------------- fused concat + LN1 -> bf16 (also writes A f32) ----------------
__global__ __launch_bounds__(256) void concat_ln_k(const float* __restrict__ x,
    const float* __restrict__ cls, const float* __restrict__ g,
    const float* __restrict__ b, float* __restrict__ A, bf* __restrict__ O)
{
  __shared__ float red[256];
  const long row = blockIdx.x; const int tid = threadIdx.x;
  const float* src = (row == 0) ? cls : (x + (row - 1) * 512);
  float v0 = src[tid], v1 = src[tid + 256];
  A[row * 512 + tid] = v0; A[row * 512 + tid + 256] = v1;
  red[tid] = v0 + v1; __syncthreads();
  for (int s = 128; s > 0; s >>= 1) { if (tid < s) red[tid] += red[tid + s]; __syncthreads(); }
  float mean = red[0] * (1.f / 512.f); __syncthreads();
  float d0 = v0 - mean, d1 = v1 - mean;
  red[tid] = d0 * d0 + d1 * d1; __syncthreads();
  for (int s = 128; s > 0; s >>= 1) { if (tid < s) red[tid] += red[tid + s]; __syncthreads(); }
  float rs = rsqrtf(red[0] * (1.f / 512.f) + 1e-5f);
  O[row * 512 + tid]       = __float2bfloat16(d0 * rs * g[tid] + b[tid]);
  O[row * 512 + tid + 256] = __float2bfloat16(d1 * rs * g[tid + 256] + b[tid + 256]);
}

// ---------------- fused LN -> bf16 ----------------
__global__ __launch_bounds__(256) void ln_bf16_k(const float* __restrict__ X,
    const float* __restrict__ g, const float* __restrict__ b,
    bf* __restrict__ O)
{
  __shared__ float red[256];
  const long row = blockIdx.x; const int tid = threadIdx.x;
  const float* r = X + row * 512;
  float v0 = r[tid], v1 = r[tid + 256];
  red[tid] = v0 + v1; __syncthreads();
  for (int s = 128; s > 0; s >>= 1) { if (tid < s) red[tid] += red[tid + s]; __syncthreads(); }
  float mean = red[0] * (1.f / 512.f); __syncthreads();
  float d0 = v0 - mean, d1 = v1 - mean;
  red[tid] = d0 * d0 + d1 * d1; __syncthreads();
  for (int s = 128; s > 0; s >>= 1) { if (tid < s) red[tid] += red[tid + s]; __syncthreads(); }
  float rs = rsqrtf(red[0] * (1.f / 512.f) + 1e-5f);
  O[row * 512 + tid]       = __float2bfloat16(d0 * rs * g[tid] + b[tid]);
  O[row * 512 + tid + 256] = __float2bfloat16(d1 * rs * g[tid + 256] + b[tid + 256]);
}

// ---------------- weight transpose f32[K][N] -> bf16[N][K] ----------------
__global__ __launch_bounds__(256) void tconv_k(const float* __restrict__ W,
    bf* __restrict__ WT, int K, int N)
{
  __shared__ float t[64][65];
  const int n0 = blockIdx.x << 6, k0 = blockIdx.y << 6;
  const int c = threadIdx.x & 63; const int r4 = threadIdx.x >> 6;
  #pragma unroll 4
  for (int i = 0; i < 16; i++) {
    int r = r4 * 16 + i;
    t[r][c] = W[(long)(k0 + r) * N + n0 + c];
  }
  __syncthreads();
  #pragma unroll 4
  for (int i = 0; i < 16; i++) {
    int r = r4 * 16 + i;
    WT[(long)(n0 + r) * K + k0 + c] = __float2bfloat16(t[c][r]);
  }
}

// ---------------- double-buffered bf16 MFMA GEMM, counted-vmcnt pipeline ----------------
// Raw s_barrier + s_waitcnt vmcnt(8): prefetch loads stay in flight across the barrier.
// EPI: 1 = f32 + bias + residual; 2 = bf16 + bias + gelu; 3 = head-major Q/K/V bf16
template<int EPI>
__global__ __launch_bounds__(256) void gemm_bf(
    const bf* __restrict__ Ag, const bf* __restrict__ Bg,
    void* __restrict__ Cg, const float* __restrict__ Res,
    const float* __restrict__ bias, int K, int N,
    bf* __restrict__ Qb, bf* __restrict__ Kb, bf* __restrict__ Vb)
{
  __shared__ __align__(16) short As[2][2][128][32];
  __shared__ __align__(16) short Bs[2][2][128][32];
  const int tid = threadIdx.x, lane = tid & 63, wid = tid >> 6;
  // XCD-aware chunked swizzle: blocks sharing an A-row panel land on one XCD.
  const int nwg = gridDim.x * gridDim.y;
  const int lin = blockIdx.y * gridDim.x + blockIdx.x;
  const int nl = (lin & 7) * (nwg >> 3) + (lin >> 3);
  const int bxi = nl % gridDim.x, byi = nl / gridDim.x;
  const int brow = byi << 7, bcol = bxi << 7;
  const int wr = (wid >> 1) << 6, wc = (wid & 1) << 6;
  const int fr = lane & 15, fs = lane >> 4;
  const int srow = lane >> 2, skp = (lane & 3) << 3;
  f32x4 acc[4][4];
  #pragma unroll
  for (int m = 0; m < 4; m++)
    #pragma unroll
    for (int n = 0; n < 4; n++) acc[m][n] = (f32x4){0.f, 0.f, 0.f, 0.f};

  const bf* Arow = Ag + (long)brow * K;
  const bf* Brow = Bg + (long)bcol * K;

  auto stage = [&](int bufi, int koff) {
    #pragma unroll
    for (int i = 0; i < 4; i++) {
      int c = (wid << 2) + i, rg = c >> 1, hf = c & 1;
      gl_lds16(Arow + (long)(rg * 16 + srow) * K + koff + hf * 32 + skp,
               &As[bufi][hf][rg * 16][0]);
      gl_lds16(Brow + (long)(rg * 16 + srow) * K + koff + hf * 32 + skp,
               &Bs[bufi][hf][rg * 16][0]);
    }
  };

  stage(0, 0);                           // 8 loads in flight (buf 0)
  const int nk = K >> 6;
  for (int t = 0; t < nk; ++t) {
    const int buf = t & 1;
    if (t + 1 < nk) {
      stage(buf ^ 1, (t + 1) << 6);      // +8 loads (prefetch) -> 16 outstanding
      asm volatile("s_waitcnt vmcnt(8)" ::: "memory");   // wait only current buf's 8
    } else {
      asm volatile("s_waitcnt vmcnt(0)" ::: "memory");
    }
    __builtin_amdgcn_s_barrier();        // all threads' current-buf loads landed
    #pragma unroll
    for (int kk = 0; kk < 2; kk++) {
      short8 a[4], b[4];
      #pragma unroll
      for (int m = 0; m < 4; m++)
        a[m] = *(const short8*)&As[buf][kk][wr + m * 16 + fr][fs * 8];
      #pragma unroll
      for (int n = 0; n < 4; n++)
        b[n] = *(const short8*)&Bs[buf][kk][wc + n * 16 + fr][fs * 8];
      #pragma unroll
      for (int m = 0; m < 4; m++)
        #pragma unroll
        for (int n = 0; n < 4; n++)
          acc[m][n] = __builtin_amdgcn_mfma_f32_16x16x32_bf16(a[m], b[n], acc[m][n], 0, 0, 0);
    }
    __builtin_amdgcn_s_barrier();        // reads of buf done before next overwrite
  }

  #pragma unroll
  for (int m = 0; m < 4; m++) {
    #pragma unroll
    for (int n = 0; n < 4; n++) {
      const int col = bcol + wc + n * 16 + fr;
      #pragma unroll
      for (int j = 0; j < 4; j++) {
        const long row = brow + wr + m * 16 + fs * 4 + j;
        float v = acc[m][n][j];
        if (EPI == 1) {
          v += bias[col] + Res[row * N + col];
          ((float*)Cg)[row * N + col] = v;
        } else if (EPI == 2) {
          v += bias[col];
          v = 0.5f * v * (1.f + erff(v * 0.70710678118654752f));
          ((bf*)Cg)[row * N + col] = __float2bfloat16(v);
        } else {
          int sect = col >> 9, h = (col >> 6) & 7, d = col & 63;
          long o = ((long)h * 8192 + row) * 64 + d;
          if (sect == 0)      Qb[o] = __float2bfloat16(v * 0.125f);
          else if (sect == 1) Kb[o] = __float2bfloat16(v);
          else                Vb[o] = __float2bfloat16(v);
        }
      }
    }
  }
}

// ---------------- pinv phase GEMM: 64x64 tiles, grid (4,4,8), XCD-swizzled per head ----------------
template<int CS, int DIAG>
__global__ __launch_bounds__(256) void pgemm_k(
    const bf* __restrict__ Ag, const bf* __restrict__ Bg,
    bf* __restrict__ Cg, bf* __restrict__ Tg, float alpha, float s)
{
  __shared__ __align__(16) short As[8][64][32];
  __shared__ __align__(16) short Bs[8][64][32];
  short (*Tt)[68] = (short(*)[68])&As[0][0][0];
  const int tid = threadIdx.x, lane = tid & 63, wid = tid >> 6;
  // chunked swizzle: each head's 16 blocks land on one XCD (nwg=128, q=16)
  const int lin = (blockIdx.z * 4 + blockIdx.y) * 4 + blockIdx.x;
  const int nl = (lin & 7) * 16 + (lin >> 3);
  const int bz = nl >> 4, rem = nl & 15;
  const long base = (long)bz << 16;
  const int brow = (rem >> 2) << 6, bcol = (rem & 3) << 6;
  const int wr = (wid >> 1) << 5, wc = (wid & 1) << 5;
  const int fr = lane & 15, fs = lane >> 4;
  const int srow = lane >> 2, skp = (lane & 3) << 3;
  const bf* Arow = Ag + base + (long)brow * 256;
  const bf* Brow = Bg + base + (long)bcol * 256;
  #pragma unroll
  for (int i = 0; i < 16; i++) {
    int c = (wid << 4) + i;
    int mat = c >> 5, c5 = c & 31, rg = c5 >> 3, ks = c5 & 7;
    const bf* src = (mat ? Brow : Arow) + (long)(rg * 16 + srow) * 256 + ks * 32 + skp;
    gl_lds16(src, mat ? &Bs[ks][rg * 16][0] : &As[ks][rg * 16][0]);
  }
  __syncthreads();
  f32x4 acc[2][2];
  #pragma unroll
  for (int m = 0; m < 2; m++)
    #pragma unroll
    for (int n = 0; n < 2; n++) acc[m][n] = (f32x4){0.f, 0.f, 0.f, 0.f};
  #pragma unroll
  for (int ks = 0; ks < 8; ks++) {
    short8 a[2], b[2];
    #pragma unroll
    for (int m = 0; m < 2; m++)
      a[m] = *(const short8*)&As[ks][wr + m * 16 + fr][fs * 8];
    #pragma unroll
    for (int n = 0; n < 2; n++)
      b[n] = *(const short8*)&Bs[ks][wc + n * 16 + fr][fs * 8];
    #pragma unroll
    for (int m = 0; m < 2; m++)
      #pragma unroll
      for (int n = 0; n < 2; n++)
        acc[m][n] = __builtin_amdgcn_mfma_f32_16x16x32_bf16(a[m], b[n], acc[m][n], 0, 0, 0);
  }
  if (CS) {
    #pragma unroll
    for (int m = 0; m < 2; m++)
      #pragma unroll
      for (int n = 0; n < 2; n++) {
        const int col = bcol + wc + n * 16 + fr;
        #pragma unroll
        for (int j = 0; j < 4; j++)
          (Cg + base)[(long)(brow + wr + m * 16 + fs * 4 + j) * 256 + col] =
              __float2bfloat16(acc[m][n][j] * alpha);
      }
  }
  __syncthreads();
  #pragma unroll
  for (int m = 0; m < 2; m++)
    #pragma unroll
    for (int n = 0; n < 2; n++) {
      const int lcol = wc + n * 16 + fr;
      #pragma unroll
      for (int j = 0; j < 4; j++) {
        const int lrow = wr + m * 16 + fs * 4 + j;
        float v = acc[m][n][j] * alpha;
        float o = DIAG ? (((brow + lrow) == (bcol + lcol)) ? (s - v) : (-v)) : v;
        Tt[lcol][lrow] = (short)f2b(o);
      }
    }
  __syncthreads();
  {
    const int lcol = tid >> 2, q = tid & 3;
    short8 w0 = *(const short8*)&Tt[lcol][q * 16];
    short8 w1 = *(const short8*)&Tt[lcol][q * 16 + 8];
    bf* dst = Tg + base + (long)(bcol + lcol) * 256 + brow + q * 16;
    *(short8*)dst = w0;
    *(short8*)(dst + 8) = w1;
  }
}

// ---------------- batched bf16 MFMA GEMM (CM only), K=256, dbuf ----------------
template<int EPI>
__global__ __launch_bounds__(256) void bgemm(
    const bf* __restrict__ Ag, const bf* __restrict__ Bg,
    void* __restrict__ Cg, bf* __restrict__ Tg,
    int Nc, float alpha, float s,
    long lda, long ldb, long ldc, long ldt,
    long sA, long sB, long sC, long sT)
{
  __shared__ __align__(16) short As[2][2][128][32];
  __shared__ __align__(16) short Bs[2][2][128][32];
  const int tid = threadIdx.x, lane = tid & 63, wid = tid >> 6;
  const int hh = blockIdx.z;
  const int brow = blockIdx.y << 7, bcol = blockIdx.x << 7;
  const int wr = (wid >> 1) << 6, wc = (wid & 1) << 6;
  const int fr = lane & 15, fs = lane >> 4;
  const int srow = lane >> 2, skp = (lane & 3) << 3;
  f32x4 acc[4][4];
  #pragma unroll
  for (int m = 0; m < 4; m++)
    #pragma unroll
    for (int n = 0; n < 4; n++) acc[m][n] = (f32x4){0.f, 0.f, 0.f, 0.f};

  const bf* Arow = Ag + hh * sA + (long)brow * lda;
  const bf* Brow = Bg + hh * sB + (long)bcol * ldb;

  auto stage = [&](int bufi, int koff) {
    #pragma unroll
    for (int i = 0; i < 4; i++) {
      int c = (wid << 2) + i, rg = c >> 1, hf = c & 1;
      gl_lds16(Arow + (long)(rg * 16 + srow) * lda + koff + hf * 32 + skp,
               &As[bufi][hf][rg * 16][0]);
      gl_lds16(Brow + (long)(rg * 16 + srow) * ldb + koff + hf * 32 + skp,
               &Bs[bufi][hf][rg * 16][0]);
    }
  };

  stage(0, 0);
  __syncthreads();
  #pragma unroll
  for (int t = 0; t < 4; ++t) {
    const int buf = t & 1;
    if (t < 3) stage(buf ^ 1, (t + 1) << 6);
    #pragma unroll
    for (int kk = 0; kk < 2; kk++) {
      short8 a[4], b[4];
      #pragma unroll
      for (int m = 0; m < 4; m++)
        a[m] = *(const short8*)&As[buf][kk][wr + m * 16 + fr][fs * 8];
      #pragma unroll
      for (int n = 0; n < 4; n++)
        b[n] = *(const short8*)&Bs[buf][kk][wc + n * 16 + fr][fs * 8];
      #pragma unroll
      for (int m = 0; m < 4; m++)
        #pragma unroll
        for (int n = 0; n < 4; n++)
          acc[m][n] = __builtin_amdgcn_mfma_f32_16x16x32_bf16(a[m], b[n], acc[m][n], 0, 0, 0);
    }
    __syncthreads();
  }

  #pragma unroll
  for (int m = 0; m < 4; m++) {
    #pragma unroll
    for (int n = 0; n < 4; n++) {
      const int col = bcol + wc + n * 16 + fr;
      const int rbase = brow + wr + m * 16 + fs * 4;
      if (EPI != 6 || col < Nc) {
        bf* Tb = Tg + hh * sT;
        short4v tv;
        #pragma unroll
        for (int j = 0; j < 4; j++) tv[j] = (short)f2b(acc[m][n][j] * alpha);
        *(short4v*)&Tb[(long)col * ldt + rbase] = tv;
      }
    }
  }
}

// ---------------- fp32 tiled GEMM (attn2 logits only) ----------------
__global__ __launch_bounds__(256) void sgemm_k(
    const float* __restrict__ A, const float* __restrict__ Bw,
    float* __restrict__ C,
    int K, long lda, long ldb, long ldc,
    long sA, long sB, long sC)
{
  __shared__ float As[16][68];
  __shared__ __align__(16) float Bs[16][68];
  const int tid = threadIdx.x;
  const int zz = blockIdx.z;
  const float* Ab = A + zz * sA;
  const float* Bb = Bw + zz * sB;
  float* Cb = C + zz * sC;
  const int brow = blockIdx.y * 64;
  const int bcol = blockIdx.x * 64;
  const int tm = tid >> 4, tn = tid & 15;
  const int lam = tid >> 2;
  const int lak = (tid & 3) << 2;
  const int lbk = tid >> 4;
  const int lbn = (tid & 15) << 2;
  float acc[4][4];
  #pragma unroll
  for (int i = 0; i < 4; i++)
    #pragma unroll
    for (int j = 0; j < 4; j++) acc[i][j] = 0.f;

  for (int k0 = 0; k0 < K; k0 += 16) {
    float4 av = *(const float4*)&Ab[(long)(brow + lam) * lda + k0 + lak];
    As[lak + 0][lam] = av.x; As[lak + 1][lam] = av.y;
    As[lak + 2][lam] = av.z; As[lak + 3][lam] = av.w;
    float4 bv = *(const float4*)&Bb[(long)(k0 + lbk) * ldb + bcol + lbn];
    *(float4*)&Bs[lbk][lbn] = bv;
    __syncthreads();
    #pragma unroll
    for (int kk = 0; kk < 16; kk++) {
      float a0 = As[kk][(tm << 2) + 0], a1 = As[kk][(tm << 2) + 1];
      float a2 = As[kk][(tm << 2) + 2], a3 = As[kk][(tm << 2) + 3];
      float b0 = Bs[kk][(tn << 2) + 0], b1 = Bs[kk][(tn << 2) + 1];
      float b2 = Bs[kk][(tn << 2) + 2], b3 = Bs[kk][(tn << 2) + 3];
      acc[0][0] += a0 * b0; acc[0][1] += a0 * b1; acc[0][2] += a0 * b2; acc[0][3] += a0 * b3;
      acc[1][0] += a1 * b0; acc[1][1] += a1 * b1; acc[1][2] += a1 * b2; acc[1][3] += a1 * b3;
      acc[2][0] += a2 * b0; acc[2][1] += a2 * b1; acc[2][2] += a2 * b2; acc[2][3] += a2 * b3;
      acc[3][0] += a3 * b0; acc[3][1] += a3 * b1; acc[3][2] += a3 * b2; acc[3][3] += a3 * b3;
    }
    __syncthreads();
  }
  #pragma unroll
  for (int i = 0; i < 4; i++) {
    const long row = brow + (tm << 2) + i;
    #pragma unroll
    for (int j = 0; j < 4; j++) {
      const int col = bcol + (tn << 2) + j;
      Cb[row * ldc + col] = acc[i][j];
    }
  }
}

// ---------------- landmarks from bf16 Q/K ----------------
__global__ __launch_bounds__(256) void landmarks_k(const bf* __restrict__ Qb,
    const bf* __restrict__ Kb,
    float* __restrict__ QL, float* __restrict__ KLT,
    bf* __restrict__ QLb, bf* __restrict__ KLb)
{
  int t = blockIdx.x * 256 + threadIdx.x;
  int d = t & 63; int m = (t >> 6) & 255; int h = t >> 14;
  const unsigned short* qp = (const unsigned short*)Qb + ((long)h * 8192 + m * 32) * 64 + d;
  const unsigned short* kp = (const unsigned short*)Kb + ((long)h * 8192 + m * 32) * 64 + d;
  float sq = 0.f, sk = 0.f;
  for (int i = 0; i < 32; i++) { sq += b2f(qp[i * 64]); sk += b2f(kp[i * 64]); }
  float qv = sq * (1.f / 32.f);
  QL[t] = qv;
  QLb[t] = __float2bfloat16(qv);
  float kv = sk * (1.f / 32.f);
  KLb[t] = __float2bfloat16(kv);
  KLT[(h << 14) + (d << 8) + m] = kv;
}

// ---------------- V transpose (bf16 -> bf16): VT[h][d][n] ----------------
__global__ __launch_bounds__(256) void vt_k(const bf* __restrict__ Vb,
    bf* __restrict__ VT)
{
  __shared__ unsigned short t[64][68];
  const int h = blockIdx.x & 7; const int n0 = (blockIdx.x >> 3) << 6;
  const int c = threadIdx.x & 63; const int r4 = threadIdx.x >> 6;
  const unsigned short* vp = (const unsigned short*)Vb;
  unsigned short* vo = (unsigned short*)VT;
  #pragma unroll 4
  for (int i = 0; i < 16; i++) {
    int r = r4 * 16 + i;
    t[r][c] = vp[((long)h * 8192 + n0 + r) * 64 + c];
  }
  __syncthreads();
  #pragma unroll 4
  for (int i = 0; i < 16; i++) {
    int d = r4 * 16 + i;
    vo[((long)(h << 6) + d) * 8192 + n0 + c] = t[c][d];
  }
}

// ---------------- row softmax, width 256, f32 in place ----------------
__global__ __launch_bounds__(256) void softmax256_k(float* __restrict__ X)
{
  __shared__ float red[256];
  const long row = blockIdx.x; const int tid = threadIdx.x;
  float v = X[row * 256 + tid];
  red[tid] = v; __syncthreads();
  for (int s = 128; s > 0; s >>= 1) { if (tid < s) red[tid] = fmaxf(red[tid], red[tid + s]); __syncthreads(); }
  float M = red[0]; __syncthreads();
  float e = __expf(v - M);
  red[tid] = e; __syncthreads();
  for (int s = 128; s > 0; s >>= 1) { if (tid < s) red[tid] += red[tid + s]; __syncthreads(); }
  float S = red[0];
  X[row * 256 + tid] = e / S;
}

// ---------------- pinv scalars ----------------
__global__ __launch_bounds__(256) void colsum_k(const float* __restrict__ X, float* __restrict__ out)
{
  int t = blockIdx.x * 256 + threadIdx.x; int h = t >> 8; int j = t & 255;
  const float* c = X + ((long)h << 16) + j;
  float s = 0.f;
  for (int i = 0; i < 256; i++) s += fabsf(c[(long)i << 8]);
  out[t] = s;
}
__global__ __launch_bounds__(256) void invscale_k(const float* __restrict__ cols,
    float* __restrict__ inv)
{
  __shared__ float red[256];
  int tid = threadIdx.x;
  float mc = -1e30f;
  for (int i = tid; i < 2048; i += 256) mc = fmaxf(mc, cols[i]);
  red[tid] = mc; __syncthreads();
  for (int s = 128; s > 0; s >>= 1) { if (tid < s) red[tid] = fmaxf(red[tid], red[tid + s]); __syncthreads(); }
  if (tid == 0) inv[0] = 1.0f / red[0];
}

// ---------------- pinv init: Xbf, z0 = X^T*inv, z0T = X*inv ----------------
__global__ __launch_bounds__(256) void xz_init_k(const float* __restrict__ ATT2,
    const float* __restrict__ inv, bf* __restrict__ Xb,
    bf* __restrict__ z0, bf* __restrict__ z0T)
{
  __shared__ float t[64][65];
  const int h = blockIdx.z;
  const int j0 = blockIdx.x << 6, i0 = blockIdx.y << 6;
  const int c = threadIdx.x & 63; const int r4 = threadIdx.x >> 6;
  const float iv = inv[0];
  #pragma unroll 4
  for (int i = 0; i < 16; i++) {
    int r = r4 * 16 + i;
    float v = ATT2[((long)h << 16) + (long)(i0 + r) * 256 + j0 + c];
    t[r][c] = v;
    Xb[((long)h << 16) + (long)(i0 + r) * 256 + j0 + c]  = __float2bfloat16(v);
    z0T[((long)h << 16) + (long)(i0 + r) * 256 + j0 + c] = __float2bfloat16(v * iv);
  }
  __syncthreads();
  #pragma unroll 4
  for (int i = 0; i < 16; i++) {
    int r = r4 * 16 + i;
    z0[((long)h << 16) + (long)(j0 + r) * 256 + i0 + c] = __float2bfloat16(t[c][r] * iv);
  }
}

// ---------------- flash attn3, XCD-swizzled per head ----------------
__global__ __launch_bounds__(256) void attn3f_k(
    const bf* __restrict__ Qlb, const bf* __restrict__ Kb, const bf* __restrict__ Vt,
    float* __restrict__ Op, float* __restrict__ Mp, float* __restrict__ Lp)
{
  __shared__ __align__(16) short Qs[2][128][32];
  __shared__ __align__(16) short Ks[2][128][32];
  __shared__ __align__(16) short Vs[4][64][32];
  __shared__ __align__(16) short Ps[4][4][32][32];
  const int tid = threadIdx.x, lane = tid & 63, wid = tid >> 6;
  const int fr = lane & 15, fs = lane >> 4;
  const int srow = lane >> 2, skp = (lane & 3) << 3;
  // grid (16,2,8): chunked swizzle keeps each head's 32 blocks on one XCD
  const int lin = (blockIdx.z * 2 + blockIdx.y) * 16 + blockIdx.x;
  const int nl = (lin & 7) * 32 + (lin >> 3);
  const int chunk = nl & 15, mt = (nl >> 4) & 1, h = nl >> 5;
  const int wrb = wid << 5;
  const bf* Qg = Qlb + ((long)h * 256 + mt * 128) * 64;
  #pragma unroll
  for (int i = 0; i < 4; i++) {
    int c = (wid << 2) + i, rg = c >> 1, hf = c & 1;
    gl_lds16(Qg + (long)(rg * 16 + srow) * 64 + hf * 32 + skp, &Qs[hf][rg * 16][0]);
  }
  f32x4 acc2[2][4];
  float mrun[2][4], lrun[2][4];
  #pragma unroll
  for (int m = 0; m < 2; m++)
    #pragma unroll
    for (int n = 0; n < 4; n++) { acc2[m][n] = (f32x4){0.f,0.f,0.f,0.f}; mrun[m][n] = -1e30f; lrun[m][n] = 0.f; }

  for (int t = 0; t < 4; t++) {
    const int key0 = (chunk << 9) + (t << 7);
    const bf* Kg = Kb + ((long)h * 8192 + key0) * 64;
    #pragma unroll
    for (int i = 0; i < 4; i++) {
      int c = (wid << 2) + i, rg = c >> 1, hf = c & 1;
      gl_lds16(Kg + (long)(rg * 16 + srow) * 64 + hf * 32 + skp, &Ks[hf][rg * 16][0]);
    }
    #pragma unroll
    for (int i = 0; i < 4; i++) {
      int c = (wid << 2) + i, dg = c >> 2, ks = c & 3;
      gl_lds16(Vt + ((long)h * 64 + dg * 16 + srow) * 8192 + key0 + ks * 32 + skp,
               &Vs[ks][dg * 16][0]);
    }
    __syncthreads();
    f32x4 lac[2][8];
    #pragma unroll
    for (int m = 0; m < 2; m++)
      #pragma unroll
      for (int n = 0; n < 8; n++) lac[m][n] = (f32x4){0.f,0.f,0.f,0.f};
    #pragma unroll
    for (int kk = 0; kk < 2; kk++) {
      short8 a[2];
      #pragma unroll
      for (int m = 0; m < 2; m++)
        a[m] = *(const short8*)&Qs[kk][wrb + m * 16 + fr][fs * 8];
      #pragma unroll
      for (int n = 0; n < 8; n++) {
        short8 b = *(const short8*)&Ks[kk][n * 16 + fr][fs * 8];
        #pragma unroll
        for (int m = 0; m < 2; m++)
          lac[m][n] = __builtin_amdgcn_mfma_f32_16x16x32_bf16(a[m], b, lac[m][n], 0, 0, 0);
      }
    }
    #pragma unroll
    for (int m = 0; m < 2; m++) {
      #pragma unroll
      for (int j = 0; j < 4; j++) {
        float tmax = lac[m][0][j];
        #pragma unroll
        for (int n = 1; n < 8; n++) tmax = fmaxf(tmax, lac[m][n][j]);
        tmax = fmaxf(tmax, __shfl_xor(tmax, 1));
        tmax = fmaxf(tmax, __shfl_xor(tmax, 2));
        tmax = fmaxf(tmax, __shfl_xor(tmax, 4));
        tmax = fmaxf(tmax, __shfl_xor(tmax, 8));
        float mnew = fmaxf(mrun[m][j], tmax);
        float sc = __expf(mrun[m][j] - mnew);
        #pragma unroll
        for (int n2 = 0; n2 < 4; n2++) acc2[m][n2][j] *= sc;
        float lsum = 0.f;
        #pragma unroll
        for (int n = 0; n < 8; n++) {
          float p = __expf(lac[m][n][j] - mnew);
          lac[m][n][j] = p; lsum += p;
        }
        lsum += __shfl_xor(lsum, 1);
        lsum += __shfl_xor(lsum, 2);
        lsum += __shfl_xor(lsum, 4);
        lsum += __shfl_xor(lsum, 8);
        lrun[m][j] = lrun[m][j] * sc + lsum;
        mrun[m][j] = mnew;
      }
    }
    #pragma unroll
    for (int m = 0; m < 2; m++)
      #pragma unroll
      for (int n = 0; n < 8; n++) {
        int col = n * 16 + fr;
        #pragma unroll
        for (int j = 0; j < 4; j++)
          Ps[wid][col >> 5][m * 16 + fs * 4 + j][col & 31] = (short)f2b(lac[m][n][j]);
      }
    #pragma unroll
    for (int ks = 0; ks < 4; ks++) {
      short8 a2[2];
      #pragma unroll
      for (int m = 0; m < 2; m++)
        a2[m] = *(const short8*)&Ps[wid][ks][m * 16 + fr][fs * 8];
      #pragma unroll
      for (int n = 0; n < 4; n++) {
        short8 b2 = *(const short8*)&Vs[ks][n * 16 + fr][fs * 8];
        #pragma unroll
        for (int m = 0; m < 2; m++)
          acc2[m][n] = __builtin_amdgcn_mfma_f32_16x16x32_bf16(a2[m], b2, acc2[m][n], 0, 0, 0);
      }
    }
    __syncthreads();
  }
  const long base = (long)(chunk * 8 + h) * 2 + mt;
  #pragma unroll
  for (int m = 0; m < 2; m++)
    #pragma unroll
    for (int n = 0; n < 4; n++) {
      int col = n * 16 + fr;
      #pragma unroll
      for (int j = 0; j < 4; j++)
        Op[base * 8192 + (long)(wrb + m * 16 + fs * 4 + j) * 64 + col] = acc2[m][n][j];
    }
  if (fr == 0) {
    #pragma unroll
    for (int m = 0; m < 2; m++)
      #pragma unroll
      for (int j = 0; j < 4; j++) {
        int r = wrb + m * 16 + fs * 4 + j;
        Mp[base * 128 + r] = mrun[m][j];
        Lp[base * 128 + r] = lrun[m][j];
      }
  }
}

// ---------------- flash attn3 combine (parallel, 128 blocks) -> AVT bf16 [h][d][m] ----------------
__global__ __launch_bounds__(256) void attn3c_k(
    const float* __restrict__ Op, const float* __restrict__ Mp,
    const float* __restrict__ Lp, bf* __restrict__ AVT)
{
  __shared__ float wm[16][16];
  __shared__ float wl[16][16];
  const int bid = blockIdx.x;
  const int h = bid >> 4, mt = (bid >> 3) & 1, rs = bid & 7;
  const int tid = threadIdx.x;
  const int r0 = rs * 16;
  {
    int c = tid >> 4, r = tid & 15;
    long idx = ((long)(c * 8 + h) * 2 + mt) * 128 + r0 + r;
    wm[c][r] = Mp[idx];
    wl[c][r] = Lp[idx];
  }
  __syncthreads();
  if (tid < 16) {
    int r = tid;
    float M = wm[0][r];
    #pragma unroll
    for (int c = 1; c < 16; c++) M = fmaxf(M, wm[c][r]);
    float D = 0.f;
    #pragma unroll
    for (int c = 0; c < 16; c++) D += __expf(wm[c][r] - M) * wl[c][r];
    float rv = 1.0f / D;
    #pragma unroll
    for (int c = 0; c < 16; c++) wm[c][r] = __expf(wm[c][r] - M) * rv;
  }
  __syncthreads();
  #pragma unroll
  for (int i = 0; i < 4; i++) {
    int idx = i * 256 + tid;
    int r = idx >> 6, d = idx & 63;
    float s = 0.f;
    #pragma unroll
    for (int c = 0; c < 16; c++)
      s += wm[c][r] * Op[((long)(c * 8 + h) * 2 + mt) * 8192 + (long)(r0 + r) * 64 + d];
    AVT[(long)h * 16384 + d * 256 + mt * 128 + r0 + r] = __float2bfloat16(s);
  }
}

// ---------------- fused attn1: logits -> softmax -> @CM -> Bhbf ----------------
__global__ __launch_bounds__(256) void attn1_k(
    const bf* __restrict__ Qb, const bf* __restrict__ KLb,
    const bf* __restrict__ CMT, bf* __restrict__ Bhb)
{
  __shared__ __align__(16) char U[65536];
  short (*As)[128][32] = (short(*)[128][32])U;
  short (*Bs)[256][32] = (short(*)[256][32])(U + 16384);
  short (*Ps)[128][32] = (short(*)[128][32])U;
  __shared__ __align__(16) short Cs[8][64][32];
  __shared__ float red[2][2][128];

  const int tid = threadIdx.x;
  const int lane = tid & 63, wid = tid >> 6;
  const int fr = lane & 15, fs = lane >> 4;
  const int srow = lane >> 2, skp = (lane & 3) << 3;
  const int n0 = blockIdx.x << 7, h = blockIdx.y;
  const int half = wid & 1, wrb = (wid >> 1) << 6;

  const bf* Aq = Qb  + (long)h * 524288 + (long)n0 * 64;
  const bf* Bk = KLb + (long)h * 16384;
  const bf* Cm = CMT + (long)h * 16384;

  for (int i = 0; i < 20; i++) {
    int c = wid * 20 + i;
    if (c < 16) {
      int rg = c >> 1, hf = c & 1;
      gl_lds16(Aq + (long)(rg * 16 + srow) * 64 + hf * 32 + skp, &As[hf][rg * 16][0]);
    } else if (c < 48) {
      int c2 = c - 16; int rg = c2 >> 1, hf = c2 & 1;
      gl_lds16(Bk + (long)(rg * 16 + srow) * 64 + hf * 32 + skp, &Bs[hf][rg * 16][0]);
    } else {
      int c3 = c - 48; int rg = c3 >> 3, ks = c3 & 7;
      gl_lds16(Cm + (long)(rg * 16 + srow) * 256 + ks * 32 + skp, &Cs[ks][rg * 16][0]);
    }
  }
  __syncthreads();

  f32x4 acc[4][8];
  #pragma unroll
  for (int m = 0; m < 4; m++)
    #pragma unroll
    for (int n = 0; n < 8; n++) acc[m][n] = (f32x4){0.f, 0.f, 0.f, 0.f};
  #pragma unroll
  for (int kk = 0; kk < 2; kk++) {
    short8 a[4];
    #pragma unroll
    for (int m = 0; m < 4; m++)
      a[m] = *(const short8*)&As[kk][wrb + m * 16 + fr][fs * 8];
    #pragma unroll
    for (int n = 0; n < 8; n++) {
      short8 b = *(const short8*)&Bs[kk][half * 128 + n * 16 + fr][fs * 8];
      #pragma unroll
      for (int m = 0; m < 4; m++)
        acc[m][n] = __builtin_amdgcn_mfma_f32_16x16x32_bf16(a[m], b, acc[m][n], 0, 0, 0);
    }
  }

  #pragma unroll
  for (int m = 0; m < 4; m++)
    #pragma unroll
    for (int j = 0; j < 4; j++) {
      float mx = -1e30f;
      #pragma unroll
      for (int n = 0; n < 8; n++) mx = fmaxf(mx, acc[m][n][j]);
      mx = fmaxf(mx, __shfl_xor(mx, 1));
      mx = fmaxf(mx, __shfl_xor(mx, 2));
      mx = fmaxf(mx, __shfl_xor(mx, 4));
      mx = fmaxf(mx, __shfl_xor(mx, 8));
      int rloc = wrb + m * 16 + fs * 4 + j;
      if (fr == 0) red[0][half][rloc] = mx;
    }
  __syncthreads();
  #pragma unroll
  for (int m = 0; m < 4; m++)
    #pragma unroll
    for (int j = 0; j < 4; j++) {
      int rloc = wrb + m * 16 + fs * 4 + j;
      float Mx = fmaxf(red[0][0][rloc], red[0][1][rloc]);
      float s = 0.f;
      #pragma unroll
      for (int n = 0; n < 8; n++) {
        float e = __expf(acc[m][n][j] - Mx);
        acc[m][n][j] = e; s += e;
      }
      s += __shfl_xor(s, 1);
      s += __shfl_xor(s, 2);
      s += __shfl_xor(s, 4);
      s += __shfl_xor(s, 8);
      if (fr == 0) red[1][half][rloc] = s;
    }
  __syncthreads();
  #pragma unroll
  for (int m = 0; m < 4; m++)
    #pragma unroll
    for (int j = 0; j < 4; j++) {
      int rloc = wrb + m * 16 + fs * 4 + j;
      float inv = 1.0f / (red[1][0][rloc] + red[1][1][rloc]);
      #pragma unroll
      for (int n = 0; n < 8; n++) {
        int col = half * 128 + n * 16 + fr;
        Ps[col >> 5][rloc][col & 31] = (short)f2b(acc[m][n][j] * inv);
      }
    }
  __syncthreads();

  f32x4 acc2[4][2];
  #pragma unroll
  for (int m = 0; m < 4; m++)
    #pragma unroll
    for (int n = 0; n < 2; n++) acc2[m][n] = (f32x4){0.f, 0.f, 0.f, 0.f};
  const int wc2 = half * 32;
  #pragma unroll
  for (int kk = 0; kk < 8; kk++) {
    short8 a2[4];
    #pragma unroll
    for (int m = 0; m < 4; m++)
      a2[m] = *(const short8*)&Ps[kk][wrb + m * 16 + fr][fs * 8];
    #pragma unroll
    for (int n = 0; n < 2; n++) {
      short8 b2 = *(const short8*)&Cs[kk][wc2 + n * 16 + fr][fs * 8];
      #pragma unroll
      for (int m = 0; m < 4; m++)
        acc2[m][n] = __builtin_amdgcn_mfma_f32_16x16x32_bf16(a2[m], b2, acc2[m][n], 0, 0, 0);
    }
  }
  #pragma unroll
  for (int m = 0; m < 4; m++)
    #pragma unroll
    for (int n = 0; n < 2; n++) {
      int col = wc2 + n * 16 + fr;
      #pragma unroll
      for (int j = 0; j < 4; j++) {
        long row = n0 + wrb + m * 16 + fs * 4 + j;
        Bhb[row * 512 + h * 64 + col] = __float2bfloat16(acc2[m][n][j]);
      }
    }
}

// ---------------- depthwise conv residual, bf16 RMW into Bhbf ----------------
__global__ __launch_bounds__(256) void convres_k(const bf* __restrict__ Vb,
    const float* __restrict__ W, bf* __restrict__ Bhb)
{
  const int gid = blockIdx.x * 256 + threadIdx.x;
  const int n = gid >> 7, q = gid & 127;
  const int j0 = q << 2, h = j0 >> 6, d0 = j0 & 63;
  float a0 = 0.f, a1 = 0.f, a2 = 0.f, a3 = 0.f;
  const unsigned short* vb = (const unsigned short*)Vb + (long)h * 524288 + d0;
  #pragma unroll
  for (int kk = 0; kk < 33; kk++) {
    int nn = n + kk - 16;
    if (nn >= 0 && nn < 8192) {
      float w = W[h * 33 + kk];
      uint2 raw = *(const uint2*)(vb + (long)nn * 64);
      a0 += w * b2f(raw.x & 0xffff); a1 += w * b2f(raw.x >> 16);
      a2 += w * b2f(raw.y & 0xffff); a3 += w * b2f(raw.y >> 16);
    }
  }
  unsigned short* o = (unsigned short*)Bhb + (long)n * 512 + j0;
  uint2 cur = *(uint2*)o;
  uint2 outv;
  outv.x = (unsigned)f2b(b2f(cur.x & 0xffff) + a0) | ((unsigned)f2b(b2f(cur.x >> 16) + a1) << 16);
  outv.y = (unsigned)f2b(b2f(cur.y & 0xffff) + a2) | ((unsigned)f2b(b2f(cur.y >> 16) + a3) << 16);
  *(uint2*)o = outv;
}

// ---------------- host ----------------
extern "C" void kernel_launch(void* const* d_in, const int* in_sizes, int n_in,
                              void* d_out, int out_size, void* d_ws, size_t ws_size,
                              hipStream_t stream)
{
  const float* x     = (const float*)d_in[0];
  const float* cls   = (const float*)d_in[1];
  const float* ln1g  = (const float*)d_in[2];
  const float* ln1b  = (const float*)d_in[3];
  const float* wqkv  = (const float*)d_in[4];
  const float* wout  = (const float*)d_in[5];
  const float* bout  = (const float*)d_in[6];
  const float* convw = (const float*)d_in[7];
  const float* ln2g  = (const float*)d_in[8];
  const float* ln2b  = (const float*)d_in[9];
  const float* w1    = (const float*)d_in[10];
  const float* b1    = (const float*)d_in[11];
  const float* w2    = (const float*)d_in[12];
  const float* b2    = (const float*)d_in[13];
  float* out = (float*)d_out;
  float* ws  = (float*)d_ws;

  float* A     = ws + 0;              // [8192][512] f32
  float* QL    = ws + 4194304;
  float* KLT   = ws + 4325376;
  float* ATT2  = ws + 4456448;
  float* csum  = ws + 4980736;
  float* inv   = ws + 4982784;        // 8
  float* Opart = ws + 4982800;        // [16][8][2][128][64] f32
  float* Mpart = ws + 7079952;        // [16][8][2][128]
  float* Lpart = ws + 7112720;
  bf* Qbf  = (bf*)(ws + 7145488);     // [8][8192][64] prescaled 0.125
  bf* Kbf  = (bf*)(ws + 9242640);
  bf* Vbf  = (bf*)(ws + 11339792);
  bf* VT   = (bf*)(ws + 13436944);    // [8][64][8192]
  bf* QLbf = (bf*)(ws + 15534096);
  bf* KLbf = (bf*)(ws + 15599632);
  bf* Xbf  = (bf*)(ws + 15665168);    // [8][256][256]
  bf* zA   = (bf*)(ws + 15927312);
  bf* zAT  = (bf*)(ws + 16189456);
  bf* zB   = (bf*)(ws + 16451600);
  bf* zBT  = (bf*)(ws + 16713744);
  bf* Gbf  = (bf*)(ws + 16975888);
  bf* TB0  = (bf*)(ws + 17238032);
  bf* TB1  = (bf*)(ws + 17500176);
  bf* AVT  = (bf*)(ws + 17762320);    // [8][64][256]
  bf* CMT  = (bf*)(ws + 17827856);
  float* R = ws + 17893392;           // reusable region
  bf* wqkvT = (bf*)R;                 // [1536][512]
  bf* ln1bf = (bf*)(R + 393216);      // [8192][512]
  bf* Bhbf  = (bf*)(R + 393216);      // aliases ln1bf after it dies
  bf* FF1bf = (bf*)R;                 // [8192][2048] after wqkvT/Bhbf dead
  bf* w1T   = Kbf;                    // aliases (Kbf dead after attn3f)
  bf* w2T   = Kbf + 1048576;
  bf* woutT = Kbf + 2097152;
  bf* ln2bf = VT;                     // aliases (VT dead after attn3f)

  concat_ln_k<<<8192, 256, 0, stream>>>(x, cls, ln1g, ln1b, A, ln1bf);
  tconv_k<<<dim3(24, 8), 256, 0, stream>>>(wqkv, wqkvT, 512, 1536);
  gemm_bf<3><<<dim3(12, 64), 256, 0, stream>>>(ln1bf, wqkvT, nullptr, nullptr, nullptr,
      512, 1536, Qbf, Kbf, Vbf);
  landmarks_k<<<512, 256, 0, stream>>>(Qbf, Kbf, QL, KLT, QLbf, KLbf);
  vt_k<<<1024, 256, 0, stream>>>(Vbf, VT);
  sgemm_k<<<dim3(4, 4, 8), 256, 0, stream>>>(QL, KLT, ATT2,
      64, 64, 256, 256, 16384, 16384, 65536);
  softmax256_k<<<2048, 256, 0, stream>>>(ATT2);
  colsum_k<<<8, 256, 0, stream>>>(ATT2, csum);
  invscale_k<<<1, 256, 0, stream>>>(csum, inv);
  xz_init_k<<<dim3(4, 4, 8), 256, 0, stream>>>(ATT2, inv, Xbf, zA, zAT);
  // pinv: 24 launches, 64x64-tile pgemm (128 blocks each), per-head XCD-grouped
  {
    bf* zc = zA; bf* zcT = zAT; bf* zn = zB; bf* znT = zBT;
    for (int it = 0; it < 6; ++it) {
      pgemm_k<1,1><<<dim3(4, 4, 8), 256, 0, stream>>>(Xbf, zcT, Gbf, TB0, 1.f, 7.f);
      pgemm_k<0,1><<<dim3(4, 4, 8), 256, 0, stream>>>(Gbf, TB0, nullptr, TB1, 1.f, 15.f);
      pgemm_k<0,1><<<dim3(4, 4, 8), 256, 0, stream>>>(Gbf, TB1, nullptr, TB0, 1.f, 13.f);
      pgemm_k<1,0><<<dim3(4, 4, 8), 256, 0, stream>>>(zc, TB0, zn, znT, 0.25f, 0.f);
      bf* t = zc; zc = zn; zn = t; t = zcT; zcT = znT; znT = t;
    }
  }
  // flash attn3 (16 key-chunks, per-head XCD-grouped) + parallel combine -> AVT
  attn3f_k<<<dim3(16, 2, 8), 256, 0, stream>>>(QLbf, Kbf, VT, Opart, Mpart, Lpart);
  attn3c_k<<<128, 256, 0, stream>>>(Opart, Mpart, Lpart, AVT);
  // CM^T = (Z @ AV)^T   (z ends at zA after 6 swaps)
  bgemm<6><<<dim3(1, 2, 8), 256, 0, stream>>>(zA, AVT, nullptr, CMT,
      64, 1.f, 0.f, 256, 256, 0, 256, 65536, 16384, 0, 16384);
  tconv_k<<<dim3(32, 8), 256, 0, stream>>>(w1, w1T, 512, 2048);
  tconv_k<<<dim3(8, 32), 256, 0, stream>>>(w2, w2T, 2048, 512);
  tconv_k<<<dim3(8, 8), 256, 0, stream>>>(wout, woutT, 512, 512);
  attn1_k<<<dim3(64, 8), 256, 0, stream>>>(Qbf, KLbf, CMT, Bhbf);
  convres_k<<<4096, 256, 0, stream>>>(Vbf, convw, Bhbf);
  gemm_bf<1><<<dim3(4, 64), 256, 0, stream>>>(Bhbf, woutT, A, A, bout, 512, 512,
      nullptr, nullptr, nullptr);
  ln_bf16_k<<<8192, 256, 0, stream>>>(A, ln2g, ln2b, ln2bf);
  gemm_bf<2><<<dim3(16, 64), 256, 0, stream>>>(ln2bf, w1T, FF1bf, nullptr, b1, 512, 2048,
      nullptr, nullptr, nullptr);
  gemm_bf<1><<<dim3(4, 64), 256, 0, stream>>>(FF1bf, w2T, out, A, b2, 2048, 512,
      nullptr, nullptr, nullptr);
}

// Round 15
// 447.349 us; speedup vs baseline: 1.1320x; 1.0160x over previous
//
#include <hip/hip_runtime.h>
#include <hip/hip_bf16.h>

typedef __attribute__((ext_vector_type(8))) short short8;
typedef __attribute__((ext_vector_type(4))) short short4v;
typedef __attribute__((ext_vector_type(4))) float f32x4;
typedef __hip_bfloat16 bf;

__device__ __forceinline__ void gl_lds16(const void* g, void* l) {
  __builtin_amdgcn_global_load_lds(
      (const __attribute__((address_space(1))) unsigned int*)g,
      (__attribute__((address_space(3))) unsigned int*)l, 16, 0, 0);
}
__device__ __forceinline__ unsigned short f2b(float f) {
  bf h = __float2bfloat16(f);
  return *reinterpret_cast<unsigned short*>(&h);
}
__device__ __forceinline__ float b2f(unsigned short u) {
  unsigned v = ((unsigned)u) << 16;
  return __uint_as_float(v);
}

// ---------------- fused concat + LN1 -> bf16 (also writes A f32) ----------------
__global__ __launch_bounds__(256) void concat_ln_k(const float* __restrict__ x,
    const float* __restrict__ cls, const float* __restrict__ g,
    const float* __restrict__ b, float* __restrict__ A, bf* __restrict__ O)
{
  __shared__ float red[256];
  const long row = blockIdx.x; const int tid = threadIdx.x;
  const float* src = (row == 0) ? cls : (x + (row - 1) * 512);
  float v0 = src[tid], v1 = src[tid + 256];
  A[row * 512 + tid] = v0; A[row * 512 + tid + 256] = v1;
  red[tid] = v0 + v1; __syncthreads();
  for (int s = 128; s > 0; s >>= 1) { if (tid < s) red[tid] += red[tid + s]; __syncthreads(); }
  float mean = red[0] * (1.f / 512.f); __syncthreads();
  float d0 = v0 - mean, d1 = v1 - mean;
  red[tid] = d0 * d0 + d1 * d1; __syncthreads();
  for (int s = 128; s > 0; s >>= 1) { if (tid < s) red[tid] += red[tid + s]; __syncthreads(); }
  float rs = rsqrtf(red[0] * (1.f / 512.f) + 1e-5f);
  O[row * 512 + tid]       = __float2bfloat16(d0 * rs * g[tid] + b[tid]);
  O[row * 512 + tid + 256] = __float2bfloat16(d1 * rs * g[tid + 256] + b[tid + 256]);
}

// ---------------- fused LN -> bf16 ----------------
__global__ __launch_bounds__(256) void ln_bf16_k(const float* __restrict__ X,
    const float* __restrict__ g, const float* __restrict__ b,
    bf* __restrict__ O)
{
  __shared__ float red[256];
  const long row = blockIdx.x; const int tid = threadIdx.x;
  const float* r = X + row * 512;
  float v0 = r[tid], v1 = r[tid + 256];
  red[tid] = v0 + v1; __syncthreads();
  for (int s = 128; s > 0; s >>= 1) { if (tid < s) red[tid] += red[tid + s]; __syncthreads(); }
  float mean = red[0] * (1.f / 512.f); __syncthreads();
  float d0 = v0 - mean, d1 = v1 - mean;
  red[tid] = d0 * d0 + d1 * d1; __syncthreads();
  for (int s = 128; s > 0; s >>= 1) { if (tid < s) red[tid] += red[tid + s]; __syncthreads(); }
  float rs = rsqrtf(red[0] * (1.f / 512.f) + 1e-5f);
  O[row * 512 + tid]       = __float2bfloat16(d0 * rs * g[tid] + b[tid]);
  O[row * 512 + tid + 256] = __float2bfloat16(d1 * rs * g[tid + 256] + b[tid + 256]);
}

// ---------------- weight transpose f32[K][N] -> bf16[N][K] ----------------
__global__ __launch_bounds__(256) void tconv_k(const float* __restrict__ W,
    bf* __restrict__ WT, int K, int N)
{
  __shared__ float t[64][65];
  const int n0 = blockIdx.x << 6, k0 = blockIdx.y << 6;
  const int c = threadIdx.x & 63; const int r4 = threadIdx.x >> 6;
  #pragma unroll 4
  for (int i = 0; i < 16; i++) {
    int r = r4 * 16 + i;
    t[r][c] = W[(long)(k0 + r) * N + n0 + c];
  }
  __syncthreads();
  #pragma unroll 4
  for (int i = 0; i < 16; i++) {
    int r = r4 * 16 + i;
    WT[(long)(n0 + r) * K + k0 + c] = __float2bfloat16(t[c][r]);
  }
}

// ---------------- BK=32 double-buffered bf16 MFMA GEMM, 32 KiB LDS (4 blocks/CU) ----------------
// Counted vmcnt(4): prefetch loads stay in flight across the barrier.
// EPI: 1 = f32 + bias + residual; 2 = bf16 + bias + gelu; 3 = head-major Q/K/V bf16
template<int EPI>
__global__ __launch_bounds__(256) void gemm_bf(
    const bf* __restrict__ Ag, const bf* __restrict__ Bg,
    void* __restrict__ Cg, const float* __restrict__ Res,
    const float* __restrict__ bias, int K, int N,
    bf* __restrict__ Qb, bf* __restrict__ Kb, bf* __restrict__ Vb)
{
  __shared__ __align__(16) short As[2][128][32];
  __shared__ __align__(16) short Bs[2][128][32];
  const int tid = threadIdx.x, lane = tid & 63, wid = tid >> 6;
  // XCD-aware chunked swizzle: blocks sharing an A-row panel land on one XCD.
  const int nwg = gridDim.x * gridDim.y;
  const int lin = blockIdx.y * gridDim.x + blockIdx.x;
  const int nl = (lin & 7) * (nwg >> 3) + (lin >> 3);
  const int bxi = nl % gridDim.x, byi = nl / gridDim.x;
  const int brow = byi << 7, bcol = bxi << 7;
  const int wr = (wid >> 1) << 6, wc = (wid & 1) << 6;
  const int fr = lane & 15, fs = lane >> 4;
  const int srow = lane >> 2, skp = (lane & 3) << 3;
  f32x4 acc[4][4];
  #pragma unroll
  for (int m = 0; m < 4; m++)
    #pragma unroll
    for (int n = 0; n < 4; n++) acc[m][n] = (f32x4){0.f, 0.f, 0.f, 0.f};

  const bf* Arow = Ag + (long)brow * K;
  const bf* Brow = Bg + (long)bcol * K;

  auto stage = [&](int bufi, int koff) {
    #pragma unroll
    for (int i = 0; i < 2; i++) {
      int rg = (wid << 1) + i;           // 0..7 row-groups of 16
      gl_lds16(Arow + (long)(rg * 16 + srow) * K + koff + skp,
               &As[bufi][rg * 16][0]);
      gl_lds16(Brow + (long)(rg * 16 + srow) * K + koff + skp,
               &Bs[bufi][rg * 16][0]);
    }
  };

  stage(0, 0);                           // 4 loads in flight (buf 0)
  const int nk = K >> 5;
  for (int t = 0; t < nk; ++t) {
    const int buf = t & 1;
    if (t + 1 < nk) {
      stage(buf ^ 1, (t + 1) << 5);      // +4 loads (prefetch) -> 8 outstanding
      asm volatile("s_waitcnt vmcnt(4)" ::: "memory");   // wait only current buf's 4
    } else {
      asm volatile("s_waitcnt vmcnt(0)" ::: "memory");
    }
    __builtin_amdgcn_s_barrier();        // all threads' current-buf loads landed
    {
      short8 a[4], b[4];
      #pragma unroll
      for (int m = 0; m < 4; m++)
        a[m] = *(const short8*)&As[buf][wr + m * 16 + fr][fs * 8];
      #pragma unroll
      for (int n = 0; n < 4; n++)
        b[n] = *(const short8*)&Bs[buf][wc + n * 16 + fr][fs * 8];
      #pragma unroll
      for (int m = 0; m < 4; m++)
        #pragma unroll
        for (int n = 0; n < 4; n++)
          acc[m][n] = __builtin_amdgcn_mfma_f32_16x16x32_bf16(a[m], b[n], acc[m][n], 0, 0, 0);
    }
    __builtin_amdgcn_s_barrier();        // reads of buf done before next overwrite
  }

  #pragma unroll
  for (int m = 0; m < 4; m++) {
    #pragma unroll
    for (int n = 0; n < 4; n++) {
      const int col = bcol + wc + n * 16 + fr;
      #pragma unroll
      for (int j = 0; j < 4; j++) {
        const long row = brow + wr + m * 16 + fs * 4 + j;
        float v = acc[m][n][j];
        if (EPI == 1) {
          v += bias[col] + Res[row * N + col];
          ((float*)Cg)[row * N + col] = v;
        } else if (EPI == 2) {
          v += bias[col];
          v = 0.5f * v * (1.f + erff(v * 0.70710678118654752f));
          ((bf*)Cg)[row * N + col] = __float2bfloat16(v);
        } else {
          int sect = col >> 9, h = (col >> 6) & 7, d = col & 63;
          long o = ((long)h * 8192 + row) * 64 + d;
          if (sect == 0)      Qb[o] = __float2bfloat16(v * 0.125f);
          else if (sect == 1) Kb[o] = __float2bfloat16(v);
          else                Vb[o] = __float2bfloat16(v);
        }
      }
    }
  }
}

// ---------------- pinv phase GEMM: 64x64 tiles, grid (4,4,8), XCD-swizzled per head ----------------
template<int CS, int DIAG>
__global__ __launch_bounds__(256) void pgemm_k(
    const bf* __restrict__ Ag, const bf* __restrict__ Bg,
    bf* __restrict__ Cg, bf* __restrict__ Tg, float alpha, float s)
{
  __shared__ __align__(16) short As[8][64][32];
  __shared__ __align__(16) short Bs[8][64][32];
  short (*Tt)[68] = (short(*)[68])&As[0][0][0];
  const int tid = threadIdx.x, lane = tid & 63, wid = tid >> 6;
  // chunked swizzle: each head's 16 blocks land on one XCD (nwg=128, q=16)
  const int lin = (blockIdx.z * 4 + blockIdx.y) * 4 + blockIdx.x;
  const int nl = (lin & 7) * 16 + (lin >> 3);
  const int bz = nl >> 4, rem = nl & 15;
  const long base = (long)bz << 16;
  const int brow = (rem >> 2) << 6, bcol = (rem & 3) << 6;
  const int wr = (wid >> 1) << 5, wc = (wid & 1) << 5;
  const int fr = lane & 15, fs = lane >> 4;
  const int srow = lane >> 2, skp = (lane & 3) << 3;
  const bf* Arow = Ag + base + (long)brow * 256;
  const bf* Brow = Bg + base + (long)bcol * 256;
  #pragma unroll
  for (int i = 0; i < 16; i++) {
    int c = (wid << 4) + i;
    int mat = c >> 5, c5 = c & 31, rg = c5 >> 3, ks = c5 & 7;
    const bf* src = (mat ? Brow : Arow) + (long)(rg * 16 + srow) * 256 + ks * 32 + skp;
    gl_lds16(src, mat ? &Bs[ks][rg * 16][0] : &As[ks][rg * 16][0]);
  }
  __syncthreads();
  f32x4 acc[2][2];
  #pragma unroll
  for (int m = 0; m < 2; m++)
    #pragma unroll
    for (int n = 0; n < 2; n++) acc[m][n] = (f32x4){0.f, 0.f, 0.f, 0.f};
  #pragma unroll
  for (int ks = 0; ks < 8; ks++) {
    short8 a[2], b[2];
    #pragma unroll
    for (int m = 0; m < 2; m++)
      a[m] = *(const short8*)&As[ks][wr + m * 16 + fr][fs * 8];
    #pragma unroll
    for (int n = 0; n < 2; n++)
      b[n] = *(const short8*)&Bs[ks][wc + n * 16 + fr][fs * 8];
    #pragma unroll
    for (int m = 0; m < 2; m++)
      #pragma unroll
      for (int n = 0; n < 2; n++)
        acc[m][n] = __builtin_amdgcn_mfma_f32_16x16x32_bf16(a[m], b[n], acc[m][n], 0, 0, 0);
  }
  if (CS) {
    #pragma unroll
    for (int m = 0; m < 2; m++)
      #pragma unroll
      for (int n = 0; n < 2; n++) {
        const int col = bcol + wc + n * 16 + fr;
        #pragma unroll
        for (int j = 0; j < 4; j++)
          (Cg + base)[(long)(brow + wr + m * 16 + fs * 4 + j) * 256 + col] =
              __float2bfloat16(acc[m][n][j] * alpha);
      }
  }
  __syncthreads();
  #pragma unroll
  for (int m = 0; m < 2; m++)
    #pragma unroll
    for (int n = 0; n < 2; n++) {
      const int lcol = wc + n * 16 + fr;
      #pragma unroll
      for (int j = 0; j < 4; j++) {
        const int lrow = wr + m * 16 + fs * 4 + j;
        float v = acc[m][n][j] * alpha;
        float o = DIAG ? (((brow + lrow) == (bcol + lcol)) ? (s - v) : (-v)) : v;
        Tt[lcol][lrow] = (short)f2b(o);
      }
    }
  __syncthreads();
  {
    const int lcol = tid >> 2, q = tid & 3;
    short8 w0 = *(const short8*)&Tt[lcol][q * 16];
    short8 w1 = *(const short8*)&Tt[lcol][q * 16 + 8];
    bf* dst = Tg + base + (long)(bcol + lcol) * 256 + brow + q * 16;
    *(short8*)dst = w0;
    *(short8*)(dst + 8) = w1;
  }
}

// ---------------- batched bf16 MFMA GEMM (CM only), K=256, dbuf ----------------
template<int EPI>
__global__ __launch_bounds__(256) void bgemm(
    const bf* __restrict__ Ag, const bf* __restrict__ Bg,
    void* __restrict__ Cg, bf* __restrict__ Tg,
    int Nc, float alpha, float s,
    long lda, long ldb, long ldc, long ldt,
    long sA, long sB, long sC, long sT)
{
  __shared__ __align__(16) short As[2][2][128][32];
  __shared__ __align__(16) short Bs[2][2][128][32];
  const int tid = threadIdx.x, lane = tid & 63, wid = tid >> 6;
  const int hh = blockIdx.z;
  const int brow = blockIdx.y << 7, bcol = blockIdx.x << 7;
  const int wr = (wid >> 1) << 6, wc = (wid & 1) << 6;
  const int fr = lane & 15, fs = lane >> 4;
  const int srow = lane >> 2, skp = (lane & 3) << 3;
  f32x4 acc[4][4];
  #pragma unroll
  for (int m = 0; m < 4; m++)
    #pragma unroll
    for (int n = 0; n < 4; n++) acc[m][n] = (f32x4){0.f, 0.f, 0.f, 0.f};

  const bf* Arow = Ag + hh * sA + (long)brow * lda;
  const bf* Brow = Bg + hh * sB + (long)bcol * ldb;

  auto stage = [&](int bufi, int koff) {
    #pragma unroll
    for (int i = 0; i < 4; i++) {
      int c = (wid << 2) + i, rg = c >> 1, hf = c & 1;
      gl_lds16(Arow + (long)(rg * 16 + srow) * lda + koff + hf * 32 + skp,
               &As[bufi][hf][rg * 16][0]);
      gl_lds16(Brow + (long)(rg * 16 + srow) * ldb + koff + hf * 32 + skp,
               &Bs[bufi][hf][rg * 16][0]);
    }
  };

  stage(0, 0);
  __syncthreads();
  #pragma unroll
  for (int t = 0; t < 4; ++t) {
    const int buf = t & 1;
    if (t < 3) stage(buf ^ 1, (t + 1) << 6);
    #pragma unroll
    for (int kk = 0; kk < 2; kk++) {
      short8 a[4], b[4];
      #pragma unroll
      for (int m = 0; m < 4; m++)
        a[m] = *(const short8*)&As[buf][kk][wr + m * 16 + fr][fs * 8];
      #pragma unroll
      for (int n = 0; n < 4; n++)
        b[n] = *(const short8*)&Bs[buf][kk][wc + n * 16 + fr][fs * 8];
      #pragma unroll
      for (int m = 0; m < 4; m++)
        #pragma unroll
        for (int n = 0; n < 4; n++)
          acc[m][n] = __builtin_amdgcn_mfma_f32_16x16x32_bf16(a[m], b[n], acc[m][n], 0, 0, 0);
    }
    __syncthreads();
  }

  #pragma unroll
  for (int m = 0; m < 4; m++) {
    #pragma unroll
    for (int n = 0; n < 4; n++) {
      const int col = bcol + wc + n * 16 + fr;
      const int rbase = brow + wr + m * 16 + fs * 4;
      if (EPI != 6 || col < Nc) {
        bf* Tb = Tg + hh * sT;
        short4v tv;
        #pragma unroll
        for (int j = 0; j < 4; j++) tv[j] = (short)f2b(acc[m][n][j] * alpha);
        *(short4v*)&Tb[(long)col * ldt + rbase] = tv;
      }
    }
  }
}

// ---------------- fp32 tiled GEMM (attn2 logits only) ----------------
__global__ __launch_bounds__(256) void sgemm_k(
    const float* __restrict__ A, const float* __restrict__ Bw,
    float* __restrict__ C,
    int K, long lda, long ldb, long ldc,
    long sA, long sB, long sC)
{
  __shared__ float As[16][68];
  __shared__ __align__(16) float Bs[16][68];
  const int tid = threadIdx.x;
  const int zz = blockIdx.z;
  const float* Ab = A + zz * sA;
  const float* Bb = Bw + zz * sB;
  float* Cb = C + zz * sC;
  const int brow = blockIdx.y * 64;
  const int bcol = blockIdx.x * 64;
  const int tm = tid >> 4, tn = tid & 15;
  const int lam = tid >> 2;
  const int lak = (tid & 3) << 2;
  const int lbk = tid >> 4;
  const int lbn = (tid & 15) << 2;
  float acc[4][4];
  #pragma unroll
  for (int i = 0; i < 4; i++)
    #pragma unroll
    for (int j = 0; j < 4; j++) acc[i][j] = 0.f;

  for (int k0 = 0; k0 < K; k0 += 16) {
    float4 av = *(const float4*)&Ab[(long)(brow + lam) * lda + k0 + lak];
    As[lak + 0][lam] = av.x; As[lak + 1][lam] = av.y;
    As[lak + 2][lam] = av.z; As[lak + 3][lam] = av.w;
    float4 bv = *(const float4*)&Bb[(long)(k0 + lbk) * ldb + bcol + lbn];
    *(float4*)&Bs[lbk][lbn] = bv;
    __syncthreads();
    #pragma unroll
    for (int kk = 0; kk < 16; kk++) {
      float a0 = As[kk][(tm << 2) + 0], a1 = As[kk][(tm << 2) + 1];
      float a2 = As[kk][(tm << 2) + 2], a3 = As[kk][(tm << 2) + 3];
      float b0 = Bs[kk][(tn << 2) + 0], b1 = Bs[kk][(tn << 2) + 1];
      float b2 = Bs[kk][(tn << 2) + 2], b3 = Bs[kk][(tn << 2) + 3];
      acc[0][0] += a0 * b0; acc[0][1] += a0 * b1; acc[0][2] += a0 * b2; acc[0][3] += a0 * b3;
      acc[1][0] += a1 * b0; acc[1][1] += a1 * b1; acc[1][2] += a1 * b2; acc[1][3] += a1 * b3;
      acc[2][0] += a2 * b0; acc[2][1] += a2 * b1; acc[2][2] += a2 * b2; acc[2][3] += a2 * b3;
      acc[3][0] += a3 * b0; acc[3][1] += a3 * b1; acc[3][2] += a3 * b2; acc[3][3] += a3 * b3;
    }
    __syncthreads();
  }
  #pragma unroll
  for (int i = 0; i < 4; i++) {
    const long row = brow + (tm << 2) + i;
    #pragma unroll
    for (int j = 0; j < 4; j++) {
      const int col = bcol + (tn << 2) + j;
      Cb[row * ldc + col] = acc[i][j];
    }
  }
}

// ---------------- landmarks from bf16 Q/K ----------------
__global__ __launch_bounds__(256) void landmarks_k(const bf* __restrict__ Qb,
    const bf* __restrict__ Kb,
    float* __restrict__ QL, float* __restrict__ KLT,
    bf* __restrict__ QLb, bf* __restrict__ KLb)
{
  int t = blockIdx.x * 256 + threadIdx.x;
  int d = t & 63; int m = (t >> 6) & 255; int h = t >> 14;
  const unsigned short* qp = (const unsigned short*)Qb + ((long)h * 8192 + m * 32) * 64 + d;
  const unsigned short* kp = (const unsigned short*)Kb + ((long)h * 8192 + m * 32) * 64 + d;
  float sq = 0.f, sk = 0.f;
  for (int i = 0; i < 32; i++) { sq += b2f(qp[i * 64]); sk += b2f(kp[i * 64]); }
  float qv = sq * (1.f / 32.f);
  QL[t] = qv;
  QLb[t] = __float2bfloat16(qv);
  float kv = sk * (1.f / 32.f);
  KLb[t] = __float2bfloat16(kv);
  KLT[(h << 14) + (d << 8) + m] = kv;
}

// ---------------- V transpose (bf16 -> bf16): VT[h][d][n] ----------------
__global__ __launch_bounds__(256) void vt_k(const bf* __restrict__ Vb,
    bf* __restrict__ VT)
{
  __shared__ unsigned short t[64][68];
  const int h = blockIdx.x & 7; const int n0 = (blockIdx.x >> 3) << 6;
  const int c = threadIdx.x & 63; const int r4 = threadIdx.x >> 6;
  const unsigned short* vp = (const unsigned short*)Vb;
  unsigned short* vo = (unsigned short*)VT;
  #pragma unroll 4
  for (int i = 0; i < 16; i++) {
    int r = r4 * 16 + i;
    t[r][c] = vp[((long)h * 8192 + n0 + r) * 64 + c];
  }
  __syncthreads();
  #pragma unroll 4
  for (int i = 0; i < 16; i++) {
    int d = r4 * 16 + i;
    vo[((long)(h << 6) + d) * 8192 + n0 + c] = t[c][d];
  }
}

// ---------------- row softmax, width 256, f32 in place ----------------
__global__ __launch_bounds__(256) void softmax256_k(float* __restrict__ X)
{
  __shared__ float red[256];
  const long row = blockIdx.x; const int tid = threadIdx.x;
  float v = X[row * 256 + tid];
  red[tid] = v; __syncthreads();
  for (int s = 128; s > 0; s >>= 1) { if (tid < s) red[tid] = fmaxf(red[tid], red[tid + s]); __syncthreads(); }
  float M = red[0]; __syncthreads();
  float e = __expf(v - M);
  red[tid] = e; __syncthreads();
  for (int s = 128; s > 0; s >>= 1) { if (tid < s) red[tid] += red[tid + s]; __syncthreads(); }
  float S = red[0];
  X[row * 256 + tid] = e / S;
}

// ---------------- pinv scalars ----------------
__global__ __launch_bounds__(256) void colsum_k(const float* __restrict__ X, float* __restrict__ out)
{
  int t = blockIdx.x * 256 + threadIdx.x; int h = t >> 8; int j = t & 255;
  const float* c = X + ((long)h << 16) + j;
  float s = 0.f;
  for (int i = 0; i < 256; i++) s += fabsf(c[(long)i << 8]);
  out[t] = s;
}
__global__ __launch_bounds__(256) void invscale_k(const float* __restrict__ cols,
    float* __restrict__ inv)
{
  __shared__ float red[256];
  int tid = threadIdx.x;
  float mc = -1e30f;
  for (int i = tid; i < 2048; i += 256) mc = fmaxf(mc, cols[i]);
  red[tid] = mc; __syncthreads();
  for (int s = 128; s > 0; s >>= 1) { if (tid < s) red[tid] = fmaxf(red[tid], red[tid + s]); __syncthreads(); }
  if (tid == 0) inv[0] = 1.0f / red[0];
}

// ---------------- pinv init: Xbf, z0 = X^T*inv, z0T = X*inv ----------------
__global__ __launch_bounds__(256) void xz_init_k(const float* __restrict__ ATT2,
    const float* __restrict__ inv, bf* __restrict__ Xb,
    bf* __restrict__ z0, bf* __restrict__ z0T)
{
  __shared__ float t[64][65];
  const int h = blockIdx.z;
  const int j0 = blockIdx.x << 6, i0 = blockIdx.y << 6;
  const int c = threadIdx.x & 63; const int r4 = threadIdx.x >> 6;
  const float iv = inv[0];
  #pragma unroll 4
  for (int i = 0; i < 16; i++) {
    int r = r4 * 16 + i;
    float v = ATT2[((long)h << 16) + (long)(i0 + r) * 256 + j0 + c];
    t[r][c] = v;
    Xb[((long)h << 16) + (long)(i0 + r) * 256 + j0 + c]  = __float2bfloat16(v);
    z0T[((long)h << 16) + (long)(i0 + r) * 256 + j0 + c] = __float2bfloat16(v * iv);
  }
  __syncthreads();
  #pragma unroll 4
  for (int i = 0; i < 16; i++) {
    int r = r4 * 16 + i;
    z0[((long)h << 16) + (long)(j0 + r) * 256 + i0 + c] = __float2bfloat16(t[c][r] * iv);
  }
}

// ---------------- flash attn3, XCD-swizzled per head ----------------
__global__ __launch_bounds__(256) void attn3f_k(
    const bf* __restrict__ Qlb, const bf* __restrict__ Kb, const bf* __restrict__ Vt,
    float* __restrict__ Op, float* __restrict__ Mp, float* __restrict__ Lp)
{
  __shared__ __align__(16) short Qs[2][128][32];
  __shared__ __align__(16) short Ks[2][128][32];
  __shared__ __align__(16) short Vs[4][64][32];
  __shared__ __align__(16) short Ps[4][4][32][32];
  const int tid = threadIdx.x, lane = tid & 63, wid = tid >> 6;
  const int fr = lane & 15, fs = lane >> 4;
  const int srow = lane >> 2, skp = (lane & 3) << 3;
  // grid (16,2,8): chunked swizzle keeps each head's 32 blocks on one XCD
  const int lin = (blockIdx.z * 2 + blockIdx.y) * 16 + blockIdx.x;
  const int nl = (lin & 7) * 32 + (lin >> 3);
  const int chunk = nl & 15, mt = (nl >> 4) & 1, h = nl >> 5;
  const int wrb = wid << 5;
  const bf* Qg = Qlb + ((long)h * 256 + mt * 128) * 64;
  #pragma unroll
  for (int i = 0; i < 4; i++) {
    int c = (wid << 2) + i, rg = c >> 1, hf = c & 1;
    gl_lds16(Qg + (long)(rg * 16 + srow) * 64 + hf * 32 + skp, &Qs[hf][rg * 16][0]);
  }
  f32x4 acc2[2][4];
  float mrun[2][4], lrun[2][4];
  #pragma unroll
  for (int m = 0; m < 2; m++)
    #pragma unroll
    for (int n = 0; n < 4; n++) { acc2[m][n] = (f32x4){0.f,0.f,0.f,0.f}; mrun[m][n] = -1e30f; lrun[m][n] = 0.f; }

  for (int t = 0; t < 4; t++) {
    const int key0 = (chunk << 9) + (t << 7);
    const bf* Kg = Kb + ((long)h * 8192 + key0) * 64;
    #pragma unroll
    for (int i = 0; i < 4; i++) {
      int c = (wid << 2) + i, rg = c >> 1, hf = c & 1;
      gl_lds16(Kg + (long)(rg * 16 + srow) * 64 + hf * 32 + skp, &Ks[hf][rg * 16][0]);
    }
    #pragma unroll
    for (int i = 0; i < 4; i++) {
      int c = (wid << 2) + i, dg = c >> 2, ks = c & 3;
      gl_lds16(Vt + ((long)h * 64 + dg * 16 + srow) * 8192 + key0 + ks * 32 + skp,
               &Vs[ks][dg * 16][0]);
    }
    __syncthreads();
    f32x4 lac[2][8];
    #pragma unroll
    for (int m = 0; m < 2; m++)
      #pragma unroll
      for (int n = 0; n < 8; n++) lac[m][n] = (f32x4){0.f,0.f,0.f,0.f};
    #pragma unroll
    for (int kk = 0; kk < 2; kk++) {
      short8 a[2];
      #pragma unroll
      for (int m = 0; m < 2; m++)
        a[m] = *(const short8*)&Qs[kk][wrb + m * 16 + fr][fs * 8];
      #pragma unroll
      for (int n = 0; n < 8; n++) {
        short8 b = *(const short8*)&Ks[kk][n * 16 + fr][fs * 8];
        #pragma unroll
        for (int m = 0; m < 2; m++)
          lac[m][n] = __builtin_amdgcn_mfma_f32_16x16x32_bf16(a[m], b, lac[m][n], 0, 0, 0);
      }
    }
    #pragma unroll
    for (int m = 0; m < 2; m++) {
      #pragma unroll
      for (int j = 0; j < 4; j++) {
        float tmax = lac[m][0][j];
        #pragma unroll
        for (int n = 1; n < 8; n++) tmax = fmaxf(tmax, lac[m][n][j]);
        tmax = fmaxf(tmax, __shfl_xor(tmax, 1));
        tmax = fmaxf(tmax, __shfl_xor(tmax, 2));
        tmax = fmaxf(tmax, __shfl_xor(tmax, 4));
        tmax = fmaxf(tmax, __shfl_xor(tmax, 8));
        float mnew = fmaxf(mrun[m][j], tmax);
        float sc = __expf(mrun[m][j] - mnew);
        #pragma unroll
        for (int n2 = 0; n2 < 4; n2++) acc2[m][n2][j] *= sc;
        float lsum = 0.f;
        #pragma unroll
        for (int n = 0; n < 8; n++) {
          float p = __expf(lac[m][n][j] - mnew);
          lac[m][n][j] = p; lsum += p;
        }
        lsum += __shfl_xor(lsum, 1);
        lsum += __shfl_xor(lsum, 2);
        lsum += __shfl_xor(lsum, 4);
        lsum += __shfl_xor(lsum, 8);
        lrun[m][j] = lrun[m][j] * sc + lsum;
        mrun[m][j] = mnew;
      }
    }
    #pragma unroll
    for (int m = 0; m < 2; m++)
      #pragma unroll
      for (int n = 0; n < 8; n++) {
        int col = n * 16 + fr;
        #pragma unroll
        for (int j = 0; j < 4; j++)
          Ps[wid][col >> 5][m * 16 + fs * 4 + j][col & 31] = (short)f2b(lac[m][n][j]);
      }
    #pragma unroll
    for (int ks = 0; ks < 4; ks++) {
      short8 a2[2];
      #pragma unroll
      for (int m = 0; m < 2; m++)
        a2[m] = *(const short8*)&Ps[wid][ks][m * 16 + fr][fs * 8];
      #pragma unroll
      for (int n = 0; n < 4; n++) {
        short8 b2 = *(const short8*)&Vs[ks][n * 16 + fr][fs * 8];
        #pragma unroll
        for (int m = 0; m < 2; m++)
          acc2[m][n] = __builtin_amdgcn_mfma_f32_16x16x32_bf16(a2[m], b2, acc2[m][n], 0, 0, 0);
      }
    }
    __syncthreads();
  }
  const long base = (long)(chunk * 8 + h) * 2 + mt;
  #pragma unroll
  for (int m = 0; m < 2; m++)
    #pragma unroll
    for (int n = 0; n < 4; n++) {
      int col = n * 16 + fr;
      #pragma unroll
      for (int j = 0; j < 4; j++)
        Op[base * 8192 + (long)(wrb + m * 16 + fs * 4 + j) * 64 + col] = acc2[m][n][j];
    }
  if (fr == 0) {
    #pragma unroll
    for (int m = 0; m < 2; m++)
      #pragma unroll
      for (int j = 0; j < 4; j++) {
        int r = wrb + m * 16 + fs * 4 + j;
        Mp[base * 128 + r] = mrun[m][j];
        Lp[base * 128 + r] = lrun[m][j];
      }
  }
}

// ---------------- flash attn3 combine (parallel, 128 blocks) -> AVT bf16 [h][d][m] ----------------
__global__ __launch_bounds__(256) void attn3c_k(
    const float* __restrict__ Op, const float* __restrict__ Mp,
    const float* __restrict__ Lp, bf* __restrict__ AVT)
{
  __shared__ float wm[16][16];
  __shared__ float wl[16][16];
  const int bid = blockIdx.x;
  const int h = bid >> 4, mt = (bid >> 3) & 1, rs = bid & 7;
  const int tid = threadIdx.x;
  const int r0 = rs * 16;
  {
    int c = tid >> 4, r = tid & 15;
    long idx = ((long)(c * 8 + h) * 2 + mt) * 128 + r0 + r;
    wm[c][r] = Mp[idx];
    wl[c][r] = Lp[idx];
  }
  __syncthreads();
  if (tid < 16) {
    int r = tid;
    float M = wm[0][r];
    #pragma unroll
    for (int c = 1; c < 16; c++) M = fmaxf(M, wm[c][r]);
    float D = 0.f;
    #pragma unroll
    for (int c = 0; c < 16; c++) D += __expf(wm[c][r] - M) * wl[c][r];
    float rv = 1.0f / D;
    #pragma unroll
    for (int c = 0; c < 16; c++) wm[c][r] = __expf(wm[c][r] - M) * rv;
  }
  __syncthreads();
  #pragma unroll
  for (int i = 0; i < 4; i++) {
    int idx = i * 256 + tid;
    int r = idx >> 6, d = idx & 63;
    float s = 0.f;
    #pragma unroll
    for (int c = 0; c < 16; c++)
      s += wm[c][r] * Op[((long)(c * 8 + h) * 2 + mt) * 8192 + (long)(r0 + r) * 64 + d];
    AVT[(long)h * 16384 + d * 256 + mt * 128 + r0 + r] = __float2bfloat16(s);
  }
}

// ---------------- fused attn1: logits -> softmax -> @CM -> Bhbf ----------------
__global__ __launch_bounds__(256) void attn1_k(
    const bf* __restrict__ Qb, const bf* __restrict__ KLb,
    const bf* __restrict__ CMT, bf* __restrict__ Bhb)
{
  __shared__ __align__(16) char U[65536];
  short (*As)[128][32] = (short(*)[128][32])U;
  short (*Bs)[256][32] = (short(*)[256][32])(U + 16384);
  short (*Ps)[128][32] = (short(*)[128][32])U;
  __shared__ __align__(16) short Cs[8][64][32];
  __shared__ float red[2][2][128];

  const int tid = threadIdx.x;
  const int lane = tid & 63, wid = tid >> 6;
  const int fr = lane & 15, fs = lane >> 4;
  const int srow = lane >> 2, skp = (lane & 3) << 3;
  const int n0 = blockIdx.x << 7, h = blockIdx.y;
  const int half = wid & 1, wrb = (wid >> 1) << 6;

  const bf* Aq = Qb  + (long)h * 524288 + (long)n0 * 64;
  const bf* Bk = KLb + (long)h * 16384;
  const bf* Cm = CMT + (long)h * 16384;

  for (int i = 0; i < 20; i++) {
    int c = wid * 20 + i;
    if (c < 16) {
      int rg = c >> 1, hf = c & 1;
      gl_lds16(Aq + (long)(rg * 16 + srow) * 64 + hf * 32 + skp, &As[hf][rg * 16][0]);
    } else if (c < 48) {
      int c2 = c - 16; int rg = c2 >> 1, hf = c2 & 1;
      gl_lds16(Bk + (long)(rg * 16 + srow) * 64 + hf * 32 + skp, &Bs[hf][rg * 16][0]);
    } else {
      int c3 = c - 48; int rg = c3 >> 3, ks = c3 & 7;
      gl_lds16(Cm + (long)(rg * 16 + srow) * 256 + ks * 32 + skp, &Cs[ks][rg * 16][0]);
    }
  }
  __syncthreads();

  f32x4 acc[4][8];
  #pragma unroll
  for (int m = 0; m < 4; m++)
    #pragma unroll
    for (int n = 0; n < 8; n++) acc[m][n] = (f32x4){0.f, 0.f, 0.f, 0.f};
  #pragma unroll
  for (int kk = 0; kk < 2; kk++) {
    short8 a[4];
    #pragma unroll
    for (int m = 0; m < 4; m++)
      a[m] = *(const short8*)&As[kk][wrb + m * 16 + fr][fs * 8];
    #pragma unroll
    for (int n = 0; n < 8; n++) {
      short8 b = *(const short8*)&Bs[kk][half * 128 + n * 16 + fr][fs * 8];
      #pragma unroll
      for (int m = 0; m < 4; m++)
        acc[m][n] = __builtin_amdgcn_mfma_f32_16x16x32_bf16(a[m], b, acc[m][n], 0, 0, 0);
    }
  }

  #pragma unroll
  for (int m = 0; m < 4; m++)
    #pragma unroll
    for (int j = 0; j < 4; j++) {
      float mx = -1e30f;
      #pragma unroll
      for (int n = 0; n < 8; n++) mx = fmaxf(mx, acc[m][n][j]);
      mx = fmaxf(mx, __shfl_xor(mx, 1));
      mx = fmaxf(mx, __shfl_xor(mx, 2));
      mx = fmaxf(mx, __shfl_xor(mx, 4));
      mx = fmaxf(mx, __shfl_xor(mx, 8));
      int rloc = wrb + m * 16 + fs * 4 + j;
      if (fr == 0) red[0][half][rloc] = mx;
    }
  __syncthreads();
  #pragma unroll
  for (int m = 0; m < 4; m++)
    #pragma unroll
    for (int j = 0; j < 4; j++) {
      int rloc = wrb + m * 16 + fs * 4 + j;
      float Mx = fmaxf(red[0][0][rloc], red[0][1][rloc]);
      float s = 0.f;
      #pragma unroll
      for (int n = 0; n < 8; n++) {
        float e = __expf(acc[m][n][j] - Mx);
        acc[m][n][j] = e; s += e;
      }
      s += __shfl_xor(s, 1);
      s += __shfl_xor(s, 2);
      s += __shfl_xor(s, 4);
      s += __shfl_xor(s, 8);
      if (fr == 0) red[1][half][rloc] = s;
    }
  __syncthreads();
  #pragma unroll
  for (int m = 0; m < 4; m++)
    #pragma unroll
    for (int j = 0; j < 4; j++) {
      int rloc = wrb + m * 16 + fs * 4 + j;
      float inv = 1.0f / (red[1][0][rloc] + red[1][1][rloc]);
      #pragma unroll
      for (int n = 0; n < 8; n++) {
        int col = half * 128 + n * 16 + fr;
        Ps[col >> 5][rloc][col & 31] = (short)f2b(acc[m][n][j] * inv);
      }
    }
  __syncthreads();

  f32x4 acc2[4][2];
  #pragma unroll
  for (int m = 0; m < 4; m++)
    #pragma unroll
    for (int n = 0; n < 2; n++) acc2[m][n] = (f32x4){0.f, 0.f, 0.f, 0.f};
  const int wc2 = half * 32;
  #pragma unroll
  for (int kk = 0; kk < 8; kk++) {
    short8 a2[4];
    #pragma unroll
    for (int m = 0; m < 4; m++)
      a2[m] = *(const short8*)&Ps[kk][wrb + m * 16 + fr][fs * 8];
    #pragma unroll
    for (int n = 0; n < 2; n++) {
      short8 b2 = *(const short8*)&Cs[kk][wc2 + n * 16 + fr][fs * 8];
      #pragma unroll
      for (int m = 0; m < 4; m++)
        acc2[m][n] = __builtin_amdgcn_mfma_f32_16x16x32_bf16(a2[m], b2, acc2[m][n], 0, 0, 0);
    }
  }
  #pragma unroll
  for (int m = 0; m < 4; m++)
    #pragma unroll
    for (int n = 0; n < 2; n++) {
      int col = wc2 + n * 16 + fr;
      #pragma unroll
      for (int j = 0; j < 4; j++) {
        long row = n0 + wrb + m * 16 + fs * 4 + j;
        Bhb[row * 512 + h * 64 + col] = __float2bfloat16(acc2[m][n][j]);
      }
    }
}

// ---------------- depthwise conv residual, bf16 RMW into Bhbf ----------------
__global__ __launch_bounds__(256) void convres_k(const bf* __restrict__ Vb,
    const float* __restrict__ W, bf* __restrict__ Bhb)
{
  const int gid = blockIdx.x * 256 + threadIdx.x;
  const int n = gid >> 7, q = gid & 127;
  const int j0 = q << 2, h = j0 >> 6, d0 = j0 & 63;
  float a0 = 0.f, a1 = 0.f, a2 = 0.f, a3 = 0.f;
  const unsigned short* vb = (const unsigned short*)Vb + (long)h * 524288 + d0;
  #pragma unroll
  for (int kk = 0; kk < 33; kk++) {
    int nn = n + kk - 16;
    if (nn >= 0 && nn < 8192) {
      float w = W[h * 33 + kk];
      uint2 raw = *(const uint2*)(vb + (long)nn * 64);
      a0 += w * b2f(raw.x & 0xffff); a1 += w * b2f(raw.x >> 16);
      a2 += w * b2f(raw.y & 0xffff); a3 += w * b2f(raw.y >> 16);
    }
  }
  unsigned short* o = (unsigned short*)Bhb + (long)n * 512 + j0;
  uint2 cur = *(uint2*)o;
  uint2 outv;
  outv.x = (unsigned)f2b(b2f(cur.x & 0xffff) + a0) | ((unsigned)f2b(b2f(cur.x >> 16) + a1) << 16);
  outv.y = (unsigned)f2b(b2f(cur.y & 0xffff) + a2) | ((unsigned)f2b(b2f(cur.y >> 16) + a3) << 16);
  *(uint2*)o = outv;
}

// ---------------- host ----------------
extern "C" void kernel_launch(void* const* d_in, const int* in_sizes, int n_in,
                              void* d_out, int out_size, void* d_ws, size_t ws_size,
                              hipStream_t stream)
{
  const float* x     = (const float*)d_in[0];
  const float* cls   = (const float*)d_in[1];
  const float* ln1g  = (const float*)d_in[2];
  const float* ln1b  = (const float*)d_in[3];
  const float* wqkv  = (const float*)d_in[4];
  const float* wout  = (const float*)d_in[5];
  const float* bout  = (const float*)d_in[6];
  const float* convw = (const float*)d_in[7];
  const float* ln2g  = (const float*)d_in[8];
  const float* ln2b  = (const float*)d_in[9];
  const float* w1    = (const float*)d_in[10];
  const float* b1    = (const float*)d_in[11];
  const float* w2    = (const float*)d_in[12];
  const float* b2    = (const float*)d_in[13];
  float* out = (float*)d_out;
  float* ws  = (float*)d_ws;

  float* A     = ws + 0;              // [8192][512] f32
  float* QL    = ws + 4194304;
  float* KLT   = ws + 4325376;
  float* ATT2  = ws + 4456448;
  float* csum  = ws + 4980736;
  float* inv   = ws + 4982784;        // 8
  float* Opart = ws + 4982800;        // [16][8][2][128][64] f32
  float* Mpart = ws + 7079952;        // [16][8][2][128]
  float* Lpart = ws + 7112720;
  bf* Qbf  = (bf*)(ws + 7145488);     // [8][8192][64] prescaled 0.125
  bf* Kbf  = (bf*)(ws + 9242640);
  bf* Vbf  = (bf*)(ws + 11339792);
  bf* VT   = (bf*)(ws + 13436944);    // [8][64][8192]
  bf* QLbf = (bf*)(ws + 15534096);
  bf* KLbf = (bf*)(ws + 15599632);
  bf* Xbf  = (bf*)(ws + 15665168);    // [8][256][256]
  bf* zA   = (bf*)(ws + 15927312);
  bf* zAT  = (bf*)(ws + 16189456);
  bf* zB   = (bf*)(ws + 16451600);
  bf* zBT  = (bf*)(ws + 16713744);
  bf* Gbf  = (bf*)(ws + 16975888);
  bf* TB0  = (bf*)(ws + 17238032);
  bf* TB1  = (bf*)(ws + 17500176);
  bf* AVT  = (bf*)(ws + 17762320);    // [8][64][256]
  bf* CMT  = (bf*)(ws + 17827856);
  float* R = ws + 17893392;           // reusable region
  bf* wqkvT = (bf*)R;                 // [1536][512]
  bf* ln1bf = (bf*)(R + 393216);      // [8192][512]
  bf* Bhbf  = (bf*)(R + 393216);      // aliases ln1bf after it dies
  bf* FF1bf = (bf*)R;                 // [8192][2048] after wqkvT/Bhbf dead
  bf* w1T   = Kbf;                    // aliases (Kbf dead after attn3f)
  bf* w2T   = Kbf + 1048576;
  bf* woutT = Kbf + 2097152;
  bf* ln2bf = VT;                     // aliases (VT dead after attn3f)

  concat_ln_k<<<8192, 256, 0, stream>>>(x, cls, ln1g, ln1b, A, ln1bf);
  tconv_k<<<dim3(24, 8), 256, 0, stream>>>(wqkv, wqkvT, 512, 1536);
  gemm_bf<3><<<dim3(12, 64), 256, 0, stream>>>(ln1bf, wqkvT, nullptr, nullptr, nullptr,
      512, 1536, Qbf, Kbf, Vbf);
  landmarks_k<<<512, 256, 0, stream>>>(Qbf, Kbf, QL, KLT, QLbf, KLbf);
  vt_k<<<1024, 256, 0, stream>>>(Vbf, VT);
  sgemm_k<<<dim3(4, 4, 8), 256, 0, stream>>>(QL, KLT, ATT2,
      64, 64, 256, 256, 16384, 16384, 65536);
  softmax256_k<<<2048, 256, 0, stream>>>(ATT2);
  colsum_k<<<8, 256, 0, stream>>>(ATT2, csum);
  invscale_k<<<1, 256, 0, stream>>>(csum, inv);
  xz_init_k<<<dim3(4, 4, 8), 256, 0, stream>>>(ATT2, inv, Xbf, zA, zAT);
  // pinv: 24 launches, 64x64-tile pgemm (128 blocks each), per-head XCD-grouped
  {
    bf* zc = zA; bf* zcT = zAT; bf* zn = zB; bf* znT = zBT;
    for (int it = 0; it < 6; ++it) {
      pgemm_k<1,1><<<dim3(4, 4, 8), 256, 0, stream>>>(Xbf, zcT, Gbf, TB0, 1.f, 7.f);
      pgemm_k<0,1><<<dim3(4, 4, 8), 256, 0, stream>>>(Gbf, TB0, nullptr, TB1, 1.f, 15.f);
      pgemm_k<0,1><<<dim3(4, 4, 8), 256, 0, stream>>>(Gbf, TB1, nullptr, TB0, 1.f, 13.f);
      pgemm_k<1,0><<<dim3(4, 4, 8), 256, 0, stream>>>(zc, TB0, zn, znT, 0.25f, 0.f);
      bf* t = zc; zc = zn; zn = t; t = zcT; zcT = znT; znT = t;
    }
  }
  // flash attn3 (16 key-chunks, per-head XCD-grouped) + parallel combine -> AVT
  attn3f_k<<<dim3(16, 2, 8), 256, 0, stream>>>(QLbf, Kbf, VT, Opart, Mpart, Lpart);
  attn3c_k<<<128, 256, 0, stream>>>(Opart, Mpart, Lpart, AVT);
  // CM^T = (Z @ AV)^T   (z ends at zA after 6 swaps)
  bgemm<6><<<dim3(1, 2, 8), 256, 0, stream>>>(zA, AVT, nullptr, CMT,
      64, 1.f, 0.f, 256, 256, 0, 256, 65536, 16384, 0, 16384);
  tconv_k<<<dim3(32, 8), 256, 0, stream>>>(w1, w1T, 512, 2048);
  tconv_k<<<dim3(8, 32), 256, 0, stream>>>(w2, w2T, 2048, 512);
  tconv_k<<<dim3(8, 8), 256, 0, stream>>>(wout, woutT, 512, 512);
  attn1_k<<<dim3(64, 8), 256, 0, stream>>>(Qbf, KLbf, CMT, Bhbf);
  convres_k<<<4096, 256, 0, stream>>>(Vbf, convw, Bhbf);
  gemm_bf<1><<<dim3(4, 64), 256, 0, stream>>>(Bhbf, woutT, A, A, bout, 512, 512,
      nullptr, nullptr, nullptr);
  ln_bf16_k<<<8192, 256, 0, stream>>>(A, ln2g, ln2b, ln2bf);
  gemm_bf<2><<<dim3(16, 64), 256, 0, stream>>>(ln2bf, w1T, FF1bf, nullptr, b1, 512, 2048,
      nullptr, nullptr, nullptr);
  gemm_bf<1><<<dim3(4, 64), 256, 0, stream>>>(FF1bf, w2T, out, A, b2, 2048, 512,
      nullptr, nullptr, nullptr);
}